// Round 6
// baseline (185.519 us; speedup 1.0000x reference)
//
#include <hip/hip_runtime.h>
#include <cmath>

#define DD 128
#define LOG2E 1.4426950408889634f

__device__ __forceinline__ float sigm(float x) { return 1.0f / (1.0f + __expf(-x)); }

// Level-0 passthrough.
__global__ void k_root(const float* __restrict__ mu_min, const float* __restrict__ mu_max,
                       const float* __restrict__ braw_min, const float* __restrict__ braw_max,
                       float* __restrict__ out) {
    int i = blockIdx.x * 256 + threadIdx.x;   // 32 blocks x 256 = 8192
    out[i] = mu_min[i];
    out[8192 + i] = mu_max[i];
    out[16384 + i] = sigm(braw_min[i]) + 1e-6f;
    out[24576 + i] = sigm(braw_max[i]) + 1e-6f;
}

// Column max over parents: block 0 -> cm_min[d] = max_p mu_min[p,d];
// block 1 -> cm_neg[d] = max_p(-mu_max[p,d]).
template<int P>
__global__ __launch_bounds__(1024)
void k_prep(const float* __restrict__ mu_min, const float* __restrict__ mu_max,
            float* __restrict__ cm_min, float* __restrict__ cm_neg) {
    __shared__ float red[8][DD];
    const int g = threadIdx.x >> 7, d = threadIdx.x & (DD - 1);
    float acc = -INFINITY;
    if (blockIdx.x == 0) {
        for (int p = g; p < P; p += 8) acc = fmaxf(acc, mu_min[p * DD + d]);
    } else {
        for (int p = g; p < P; p += 8) acc = fmaxf(acc, -mu_max[p * DD + d]);
    }
    red[g][d] = acc;
    __syncthreads();
    if (threadIdx.x < DD) {
        float a = red[0][d];
        #pragma unroll
        for (int g2 = 1; g2 < 8; ++g2) a = fmaxf(a, red[g2][d]);
        (blockIdx.x == 0 ? cm_min : cm_neg)[d] = a;
    }
}

// Pack parent arrays into float2 (mu_min,mu_max) / (b_min,b_max), plus a sentinel
// pad row at p=P: mu2=(-1e38,+1e38) -> exp2 terms underflow to exactly 0;
// bb2=(0,0) -> contributes 0 to beta sums.
template<int P>
__global__ void k_pack(const float* __restrict__ mu_min, const float* __restrict__ mu_max,
                       const float* __restrict__ b_min, const float* __restrict__ b_max,
                       float2* __restrict__ mu2, float2* __restrict__ bb2) {
    int i = blockIdx.x * 1024 + threadIdx.x;
    if (i >= (P + 1) * DD) return;
    if (i < P * DD) {
        mu2[i] = make_float2(mu_min[i], mu_max[i]);
        bb2[i] = make_float2(b_min[i], b_max[i]);
    } else {
        mu2[i] = make_float2(-1e38f, 1e38f);
        bb2[i] = make_float2(0.0f, 0.0f);
    }
}

// NT = TC*128 threads: child j = tid>>7, dim d = tid&127.
// Pass A: ballot-compacted present-parent BYTE-ROW-OFFSET list (p<<10), padded to
//         a multiple of 8 with sentinel P<<10.
// Pass B: beta sums over present list (packed float2 loads).
// Pass C: s = sum_present exp2(fma(mu, r*log2e, -M*r*log2e)) (packed float2 loads).
template<int P, int TC, int NT>
__global__ __launch_bounds__(NT)
void k_levelc(const float* __restrict__ logits, const float* __restrict__ u,
              const float2* __restrict__ bb2, const float2* __restrict__ mu2,
              const float* __restrict__ cm_min, const float* __restrict__ cm_neg,
              float* __restrict__ o_mu_min, float* __restrict__ o_mu_max,
              float* __restrict__ o_b_min, float* __restrict__ o_b_max) {
    __shared__ __align__(16) int plist[TC * P];
    __shared__ int npres[TC];
    __shared__ int npadsh[TC];
    const int tid = threadIdx.x;
    const int c0 = blockIdx.x * TC;
    const int lane = tid & 63;
    if (tid < TC) npres[tid] = 0;
    __syncthreads();

    // pass A (each wave's i-range stays within one j since P%64==0)
    for (int i = tid; i < TC * P; i += NT) {
        int j = i / P;
        int p = i - j * P;
        int idx = (c0 + j) * P + p;
        float uu = u[idx] + 1e-10f;
        float g = -__logf(-__logf(uu) + 1e-10f);
        bool pres = (logits[idx] + g) > 0.0f;
        unsigned long long m = __ballot(pres);
        int base = 0;
        if (lane == 0) base = atomicAdd(&npres[j], (int)__popcll(m));
        base = __shfl(base, 0);
        if (pres) {
            int pos = __popcll(m & ((1ull << lane) - 1));
            plist[j * P + base + pos] = p << 10;   // byte offset of row p
        }
    }
    __syncthreads();
    if (tid < TC) {
        int n = npres[tid];
        int npd = (n + 7) & ~7;
        for (int k = n; k < npd; ++k) plist[tid * P + k] = P << 10;  // sentinel row
        npadsh[tid] = npd;
    }
    __syncthreads();

    const int j = tid >> 7;
    const int d = tid & (DD - 1);
    const int n = npres[j];
    const int npad = npadsh[j];
    const int* pl = &plist[j * P];
    const unsigned d8 = (unsigned)(d << 3);
    const char* bbc = (const char*)bb2;
    const char* muc = (const char*)mu2;

    // pass B: beta sums over present parents
    float dmn0 = 0.f, dmn1 = 0.f, dmx0 = 0.f, dmx1 = 0.f;
    for (int k = 0; k < npad; k += 8) {
        int4 A = *(const int4*)(pl + k);
        int4 B = *(const int4*)(pl + k + 4);
        float2 q0 = *(const float2*)(bbc + ((unsigned)A.x + d8));
        float2 q1 = *(const float2*)(bbc + ((unsigned)A.y + d8));
        float2 q2 = *(const float2*)(bbc + ((unsigned)A.z + d8));
        float2 q3 = *(const float2*)(bbc + ((unsigned)A.w + d8));
        float2 q4 = *(const float2*)(bbc + ((unsigned)B.x + d8));
        float2 q5 = *(const float2*)(bbc + ((unsigned)B.y + d8));
        float2 q6 = *(const float2*)(bbc + ((unsigned)B.z + d8));
        float2 q7 = *(const float2*)(bbc + ((unsigned)B.w + d8));
        dmn0 += (q0.x + q2.x) + (q4.x + q6.x);
        dmn1 += (q1.x + q3.x) + (q5.x + q7.x);
        dmx0 += (q0.y + q2.y) + (q4.y + q6.y);
        dmx1 += (q1.y + q3.y) + (q5.y + q7.y);
    }

    const float wsv = (float)n + 1e-10f;
    const float bmin = (dmn0 + dmn1) / wsv;
    const float bmax = (dmx0 + dmx1) / wsv;
    const float rmin = 1.0f / fmaxf(bmin, 1e-30f);
    const float nrmax = -1.0f / fmaxf(bmax, 1e-30f);
    const float Mmm = cm_min[d];
    const float Mng = cm_neg[d];
    const float rmin2  = rmin * LOG2E;          // fold log2e -> use exp2 (native v_exp)
    const float nrmax2 = nrmax * LOG2E;
    const float negM1 = -rmin2 * Mmm;           // arg1 = (mm - Mmm)*rmin*log2e <= ~0
    const float negM2 = nrmax2 * Mng;           // arg2 = (-mx - Mng)*rmax*log2e <= ~0

    // pass C
    float s10 = 0.f, s11 = 0.f, s20 = 0.f, s21 = 0.f;
    for (int k = 0; k < npad; k += 8) {
        int4 A = *(const int4*)(pl + k);
        int4 B = *(const int4*)(pl + k + 4);
        float2 q0 = *(const float2*)(muc + ((unsigned)A.x + d8));
        float2 q1 = *(const float2*)(muc + ((unsigned)A.y + d8));
        float2 q2 = *(const float2*)(muc + ((unsigned)A.z + d8));
        float2 q3 = *(const float2*)(muc + ((unsigned)A.w + d8));
        float2 q4 = *(const float2*)(muc + ((unsigned)B.x + d8));
        float2 q5 = *(const float2*)(muc + ((unsigned)B.y + d8));
        float2 q6 = *(const float2*)(muc + ((unsigned)B.z + d8));
        float2 q7 = *(const float2*)(muc + ((unsigned)B.w + d8));
        s10 += exp2f(fmaf(q0.x, rmin2, negM1));
        s11 += exp2f(fmaf(q1.x, rmin2, negM1));
        s10 += exp2f(fmaf(q2.x, rmin2, negM1));
        s11 += exp2f(fmaf(q3.x, rmin2, negM1));
        s10 += exp2f(fmaf(q4.x, rmin2, negM1));
        s11 += exp2f(fmaf(q5.x, rmin2, negM1));
        s10 += exp2f(fmaf(q6.x, rmin2, negM1));
        s11 += exp2f(fmaf(q7.x, rmin2, negM1));
        s20 += exp2f(fmaf(q0.y, nrmax2, negM2));
        s21 += exp2f(fmaf(q1.y, nrmax2, negM2));
        s20 += exp2f(fmaf(q2.y, nrmax2, negM2));
        s21 += exp2f(fmaf(q3.y, nrmax2, negM2));
        s20 += exp2f(fmaf(q4.y, nrmax2, negM2));
        s21 += exp2f(fmaf(q5.y, nrmax2, negM2));
        s20 += exp2f(fmaf(q6.y, nrmax2, negM2));
        s21 += exp2f(fmaf(q7.y, nrmax2, negM2));
    }

    const float S1 = fmaxf(s10 + s11, 1e-35f);
    const float S2 = fmaxf(s20 + s21, 1e-35f);
    const int idx = (c0 + j) * DD + d;
    o_mu_min[idx] = bmin * fmaf(rmin, Mmm, __logf(S1));
    o_mu_max[idx] = -bmax * fmaf(-nrmax, Mng, __logf(S2));
    o_b_min[idx]  = bmin;
    o_b_max[idx]  = bmax;
}

extern "C" void kernel_launch(void* const* d_in, const int* in_sizes, int n_in,
                              void* d_out, int out_size, void* d_ws, size_t ws_size,
                              hipStream_t stream) {
    const float* mu_min0  = (const float*)d_in[0];
    const float* mu_max0  = (const float*)d_in[1];
    const float* braw_min = (const float*)d_in[2];
    const float* braw_max = (const float*)d_in[3];
    const float* adj0     = (const float*)d_in[4];   // (512, 64)
    const float* adj1     = (const float*)d_in[5];   // (2048, 512)
    const float* u0       = (const float*)d_in[6];   // (1, 512, 64)
    const float* u1       = (const float*)d_in[7];   // (1, 2048, 512)
    float* out = (float*)d_out;
    float* ws = (float*)d_ws;

    // workspace layout (f32 elements)
    float*  cm0_min = ws;                  // 128
    float*  cm0_neg = ws + 128;
    float*  cm1_min = ws + 256;
    float*  cm1_neg = ws + 384;
    float2* mu2_0 = (float2*)(ws + 512);            // (64+1)*128 float2
    float2* bb2_0 = mu2_0 + 65 * DD;
    float2* mu2_1 = bb2_0 + 65 * DD;                // (512+1)*128 float2
    float2* bb2_1 = mu2_1 + 513 * DD;               // total ~1.19 MB

    // out offsets (f32): 0:mu_min0 8192:mu_max0 16384:bmin0 24576:bmax0
    // 32768:mu_min1 98304:mu_max1 163840:b_min1 229376:b_max1 (each 65536)
    // 294912:mu_min2 557056:mu_max2 819200:b_min2 1081344:b_max2 (each 262144)

    k_root<<<dim3(32), dim3(256), 0, stream>>>(mu_min0, mu_max0, braw_min, braw_max, out);

    k_prep<64><<<dim3(2), dim3(1024), 0, stream>>>(mu_min0, mu_max0, cm0_min, cm0_neg);
    k_pack<64><<<dim3(9), dim3(1024), 0, stream>>>(mu_min0, mu_max0,
                                                   out + 16384, out + 24576, mu2_0, bb2_0);

    k_levelc<64, 2, 256><<<dim3(256), dim3(256), 0, stream>>>(
        adj0, u0, bb2_0, mu2_0, cm0_min, cm0_neg,
        out + 32768, out + 98304, out + 163840, out + 229376);

    k_prep<512><<<dim3(2), dim3(1024), 0, stream>>>(out + 32768, out + 98304, cm1_min, cm1_neg);
    k_pack<512><<<dim3(65), dim3(1024), 0, stream>>>(out + 32768, out + 98304,
                                                     out + 163840, out + 229376, mu2_1, bb2_1);

    k_levelc<512, 4, 512><<<dim3(512), dim3(512), 0, stream>>>(
        adj1, u1, bb2_1, mu2_1, cm1_min, cm1_neg,
        out + 294912, out + 557056, out + 819200, out + 1081344);
}

// Round 7
// 177.960 us; speedup vs baseline: 1.0425x; 1.0425x over previous
//
#include <hip/hip_runtime.h>
#include <cmath>

#define DD 128
#define LOG2E 1.4426950408889634f

__device__ __forceinline__ float sigm(float x) { return 1.0f / (1.0f + __expf(-x)); }

// Level-0 passthrough.
__global__ void k_root(const float* __restrict__ mu_min, const float* __restrict__ mu_max,
                       const float* __restrict__ braw_min, const float* __restrict__ braw_max,
                       float* __restrict__ out) {
    int i = blockIdx.x * 256 + threadIdx.x;   // 32 blocks x 256 = 8192
    out[i] = mu_min[i];
    out[8192 + i] = mu_max[i];
    out[16384 + i] = sigm(braw_min[i]) + 1e-6f;
    out[24576 + i] = sigm(braw_max[i]) + 1e-6f;
}

// Column max over parents: block 0 -> cm_min[d] = max_p mu_min[p,d];
// block 1 -> cm_neg[d] = max_p(-mu_max[p,d]).
template<int P>
__global__ __launch_bounds__(1024)
void k_prep(const float* __restrict__ mu_min, const float* __restrict__ mu_max,
            float* __restrict__ cm_min, float* __restrict__ cm_neg) {
    __shared__ float red[8][DD];
    const int g = threadIdx.x >> 7, d = threadIdx.x & (DD - 1);
    float acc = -INFINITY;
    if (blockIdx.x == 0) {
        for (int p = g; p < P; p += 8) acc = fmaxf(acc, mu_min[p * DD + d]);
    } else {
        for (int p = g; p < P; p += 8) acc = fmaxf(acc, -mu_max[p * DD + d]);
    }
    red[g][d] = acc;
    __syncthreads();
    if (threadIdx.x < DD) {
        float a = red[0][d];
        #pragma unroll
        for (int g2 = 1; g2 < 8; ++g2) a = fmaxf(a, red[g2][d]);
        (blockIdx.x == 0 ? cm_min : cm_neg)[d] = a;
    }
}

// Pack parent arrays into float2 (mu_min,mu_max)/(b_min,b_max) + sentinel row p=P:
// mu2=(-1e38,+1e38) -> exp2 underflows to exactly 0; bb2=(0,0) -> adds 0.
template<int P>
__global__ void k_pack(const float* __restrict__ mu_min, const float* __restrict__ mu_max,
                       const float* __restrict__ b_min, const float* __restrict__ b_max,
                       float2* __restrict__ mu2, float2* __restrict__ bb2) {
    int i = blockIdx.x * 1024 + threadIdx.x;
    if (i >= (P + 1) * DD) return;
    if (i < P * DD) {
        mu2[i] = make_float2(mu_min[i], mu_max[i]);
        bb2[i] = make_float2(b_min[i], b_max[i]);
    } else {
        mu2[i] = make_float2(-1e38f, 1e38f);
        bb2[i] = make_float2(0.0f, 0.0f);
    }
}

// NT=512 threads: h=tid>>8 (parent-list half), j=(tid>>7)&1 (child of 2), d=tid&127.
// Pass A: ballot-compacted present-parent byte-row-offsets (p<<10), padded to x8
//         with sentinel. Pass B: beta sums over half-list; LDS-combine.
// Pass C: sum exp2(fma(mu, r*log2e, -M*r*log2e)) over half-list; LDS-combine.
template<int P, int NT>
__global__ __launch_bounds__(NT, 8)
void k_levelc(const float* __restrict__ logits, const float* __restrict__ u,
              const float2* __restrict__ bb2, const float2* __restrict__ mu2,
              const float* __restrict__ cm_min, const float* __restrict__ cm_neg,
              float* __restrict__ o_mu_min, float* __restrict__ o_mu_max,
              float* __restrict__ o_b_min, float* __restrict__ o_b_max) {
    constexpr int TC = 2;
    __shared__ __align__(16) int plist[TC * P];
    __shared__ int npres[TC];
    __shared__ int npadsh[TC];
    __shared__ float redA[2][TC][DD];
    __shared__ float redB[2][TC][DD];
    const int tid = threadIdx.x;
    const int c0 = blockIdx.x * TC;
    const int lane = tid & 63;
    if (tid < TC) npres[tid] = 0;
    __syncthreads();

    // pass A (P%64==0 so each wave's i-range stays within one j)
    for (int i = tid; i < TC * P; i += NT) {
        int j = i / P;
        int p = i - j * P;
        int idx = (c0 + j) * P + p;
        float uu = u[idx] + 1e-10f;
        float g = -__logf(-__logf(uu) + 1e-10f);
        bool pres = (logits[idx] + g) > 0.0f;
        unsigned long long m = __ballot(pres);
        int base = 0;
        if (lane == 0) base = atomicAdd(&npres[j], (int)__popcll(m));
        base = __shfl(base, 0);
        if (pres) {
            int pos = __popcll(m & ((1ull << lane) - 1));
            plist[j * P + base + pos] = p << 10;   // byte row offset
        }
    }
    __syncthreads();
    if (tid < TC) {
        int n = npres[tid];
        int npd = (n + 7) & ~7;
        for (int k = n; k < npd; ++k) plist[tid * P + k] = P << 10;  // sentinel
        npadsh[tid] = npd;
    }
    __syncthreads();

    const int h = tid >> 8;
    const int j = (tid >> 7) & (TC - 1);
    const int d = tid & (DD - 1);
    const int n = npres[j];
    const int npad = npadsh[j];
    const int* pl = &plist[j * P];
    const unsigned d8 = (unsigned)(d << 3);
    const char* bbc = (const char*)bb2;
    const char* muc = (const char*)mu2;

    // pass B: beta sums over this half's share (interleaved 8-blocks)
    float dmn0 = 0.f, dmn1 = 0.f, dmx0 = 0.f, dmx1 = 0.f;
    for (int k = h * 8; k < npad; k += 16) {
        int4 A = *(const int4*)(pl + k);
        int4 B = *(const int4*)(pl + k + 4);
        float2 q0 = *(const float2*)(bbc + ((unsigned)A.x + d8));
        float2 q1 = *(const float2*)(bbc + ((unsigned)A.y + d8));
        float2 q2 = *(const float2*)(bbc + ((unsigned)A.z + d8));
        float2 q3 = *(const float2*)(bbc + ((unsigned)A.w + d8));
        float2 q4 = *(const float2*)(bbc + ((unsigned)B.x + d8));
        float2 q5 = *(const float2*)(bbc + ((unsigned)B.y + d8));
        float2 q6 = *(const float2*)(bbc + ((unsigned)B.z + d8));
        float2 q7 = *(const float2*)(bbc + ((unsigned)B.w + d8));
        dmn0 += (q0.x + q2.x) + (q4.x + q6.x);
        dmn1 += (q1.x + q3.x) + (q5.x + q7.x);
        dmx0 += (q0.y + q2.y) + (q4.y + q6.y);
        dmx1 += (q1.y + q3.y) + (q5.y + q7.y);
    }
    redA[h][j][d] = dmn0 + dmn1;
    redB[h][j][d] = dmx0 + dmx1;
    __syncthreads();

    const float wsv = (float)n + 1e-10f;
    const float bmin = (redA[0][j][d] + redA[1][j][d]) / wsv;
    const float bmax = (redB[0][j][d] + redB[1][j][d]) / wsv;
    const float rmin = 1.0f / fmaxf(bmin, 1e-30f);
    const float nrmax = -1.0f / fmaxf(bmax, 1e-30f);
    const float Mmm = cm_min[d];
    const float Mng = cm_neg[d];
    const float rmin2  = rmin * LOG2E;
    const float nrmax2 = nrmax * LOG2E;
    const float negM1 = -rmin2 * Mmm;
    const float negM2 = nrmax2 * Mng;
    __syncthreads();   // before reusing redA/redB

    // pass C
    float s10 = 0.f, s11 = 0.f, s20 = 0.f, s21 = 0.f;
    for (int k = h * 8; k < npad; k += 16) {
        int4 A = *(const int4*)(pl + k);
        int4 B = *(const int4*)(pl + k + 4);
        float2 q0 = *(const float2*)(muc + ((unsigned)A.x + d8));
        float2 q1 = *(const float2*)(muc + ((unsigned)A.y + d8));
        float2 q2 = *(const float2*)(muc + ((unsigned)A.z + d8));
        float2 q3 = *(const float2*)(muc + ((unsigned)A.w + d8));
        float2 q4 = *(const float2*)(muc + ((unsigned)B.x + d8));
        float2 q5 = *(const float2*)(muc + ((unsigned)B.y + d8));
        float2 q6 = *(const float2*)(muc + ((unsigned)B.z + d8));
        float2 q7 = *(const float2*)(muc + ((unsigned)B.w + d8));
        s10 += __builtin_amdgcn_exp2f(fmaf(q0.x, rmin2, negM1));
        s11 += __builtin_amdgcn_exp2f(fmaf(q1.x, rmin2, negM1));
        s10 += __builtin_amdgcn_exp2f(fmaf(q2.x, rmin2, negM1));
        s11 += __builtin_amdgcn_exp2f(fmaf(q3.x, rmin2, negM1));
        s10 += __builtin_amdgcn_exp2f(fmaf(q4.x, rmin2, negM1));
        s11 += __builtin_amdgcn_exp2f(fmaf(q5.x, rmin2, negM1));
        s10 += __builtin_amdgcn_exp2f(fmaf(q6.x, rmin2, negM1));
        s11 += __builtin_amdgcn_exp2f(fmaf(q7.x, rmin2, negM1));
        s20 += __builtin_amdgcn_exp2f(fmaf(q0.y, nrmax2, negM2));
        s21 += __builtin_amdgcn_exp2f(fmaf(q1.y, nrmax2, negM2));
        s20 += __builtin_amdgcn_exp2f(fmaf(q2.y, nrmax2, negM2));
        s21 += __builtin_amdgcn_exp2f(fmaf(q3.y, nrmax2, negM2));
        s20 += __builtin_amdgcn_exp2f(fmaf(q4.y, nrmax2, negM2));
        s21 += __builtin_amdgcn_exp2f(fmaf(q5.y, nrmax2, negM2));
        s20 += __builtin_amdgcn_exp2f(fmaf(q6.y, nrmax2, negM2));
        s21 += __builtin_amdgcn_exp2f(fmaf(q7.y, nrmax2, negM2));
    }
    redA[h][j][d] = s10 + s11;
    redB[h][j][d] = s20 + s21;
    __syncthreads();

    if (h == 0) {
        const float S1 = fmaxf(redA[0][j][d] + redA[1][j][d], 1e-35f);
        const float S2 = fmaxf(redB[0][j][d] + redB[1][j][d], 1e-35f);
        const int idx = (c0 + j) * DD + d;
        o_mu_min[idx] = bmin * fmaf(rmin, Mmm, __logf(S1));
        o_mu_max[idx] = -bmax * fmaf(-nrmax, Mng, __logf(S2));
        o_b_min[idx]  = bmin;
        o_b_max[idx]  = bmax;
    }
}

extern "C" void kernel_launch(void* const* d_in, const int* in_sizes, int n_in,
                              void* d_out, int out_size, void* d_ws, size_t ws_size,
                              hipStream_t stream) {
    const float* mu_min0  = (const float*)d_in[0];
    const float* mu_max0  = (const float*)d_in[1];
    const float* braw_min = (const float*)d_in[2];
    const float* braw_max = (const float*)d_in[3];
    const float* adj0     = (const float*)d_in[4];   // (512, 64)
    const float* adj1     = (const float*)d_in[5];   // (2048, 512)
    const float* u0       = (const float*)d_in[6];   // (1, 512, 64)
    const float* u1       = (const float*)d_in[7];   // (1, 2048, 512)
    float* out = (float*)d_out;
    float* ws = (float*)d_ws;

    float*  cm0_min = ws;
    float*  cm0_neg = ws + 128;
    float*  cm1_min = ws + 256;
    float*  cm1_neg = ws + 384;
    float2* mu2_0 = (float2*)(ws + 512);            // (64+1)*128 float2
    float2* bb2_0 = mu2_0 + 65 * DD;
    float2* mu2_1 = bb2_0 + 65 * DD;                // (512+1)*128 float2
    float2* bb2_1 = mu2_1 + 513 * DD;               // total ~1.19 MB

    // out offsets (f32): 0:mu_min0 8192:mu_max0 16384:bmin0 24576:bmax0
    // 32768:mu_min1 98304:mu_max1 163840:b_min1 229376:b_max1 (each 65536)
    // 294912:mu_min2 557056:mu_max2 819200:b_min2 1081344:b_max2 (each 262144)

    k_root<<<dim3(32), dim3(256), 0, stream>>>(mu_min0, mu_max0, braw_min, braw_max, out);

    k_prep<64><<<dim3(2), dim3(1024), 0, stream>>>(mu_min0, mu_max0, cm0_min, cm0_neg);
    k_pack<64><<<dim3(9), dim3(1024), 0, stream>>>(mu_min0, mu_max0,
                                                   out + 16384, out + 24576, mu2_0, bb2_0);

    k_levelc<64, 512><<<dim3(256), dim3(512), 0, stream>>>(
        adj0, u0, bb2_0, mu2_0, cm0_min, cm0_neg,
        out + 32768, out + 98304, out + 163840, out + 229376);

    k_prep<512><<<dim3(2), dim3(1024), 0, stream>>>(out + 32768, out + 98304, cm1_min, cm1_neg);
    k_pack<512><<<dim3(65), dim3(1024), 0, stream>>>(out + 32768, out + 98304,
                                                     out + 163840, out + 229376, mu2_1, bb2_1);

    k_levelc<512, 512><<<dim3(1024), dim3(512), 0, stream>>>(
        adj1, u1, bb2_1, mu2_1, cm1_min, cm1_neg,
        out + 294912, out + 557056, out + 819200, out + 1081344);
}

// Round 8
// 167.084 us; speedup vs baseline: 1.1103x; 1.0651x over previous
//
#include <hip/hip_runtime.h>
#include <cmath>

#define DD 128
#define LOG2E 1.4426950408889634f

__device__ __forceinline__ float sigm(float x) { return 1.0f / (1.0f + __expf(-x)); }

// order-preserving float<->uint encoding for atomicMax
__device__ __forceinline__ unsigned fenc(float f) {
    unsigned b = __float_as_uint(f);
    return (b & 0x80000000u) ? ~b : (b | 0x80000000u);
}
__device__ __forceinline__ float fdec(unsigned e) {
    return (e & 0x80000000u) ? __uint_as_float(e ^ 0x80000000u) : __uint_as_float(~e);
}

// Level-0 passthrough + zero the 4x128 encoded col-max slots (block 0).
__global__ void k_root(const float* __restrict__ mu_min, const float* __restrict__ mu_max,
                       const float* __restrict__ braw_min, const float* __restrict__ braw_max,
                       float* __restrict__ out, unsigned* __restrict__ cm_enc) {
    int i = blockIdx.x * 256 + threadIdx.x;   // 32 blocks x 256 = 8192
    out[i] = mu_min[i];
    out[8192 + i] = mu_max[i];
    out[16384 + i] = sigm(braw_min[i]) + 1e-6f;
    out[24576 + i] = sigm(braw_max[i]) + 1e-6f;
    if (blockIdx.x == 0) {
        cm_enc[threadIdx.x] = 0u;
        cm_enc[threadIdx.x + 256] = 0u;
    }
}

// Fused pack + column-max. Packs parent arrays into float2 (mu_min,mu_max)/(b_min,b_max)
// (+ sentinel row p=P: mu2=(-1e38,+1e38) -> exp2 underflows to exact 0; bb2=(0,0)),
// and atomically maxes per-d column maxima (encoded uint).
template<int P, int RPB>
__global__ __launch_bounds__(512)
void k_packprep(const float* __restrict__ mu_min, const float* __restrict__ mu_max,
                const float* __restrict__ b_min, const float* __restrict__ b_max,
                float2* __restrict__ mu2, float2* __restrict__ bb2,
                unsigned* __restrict__ e_min, unsigned* __restrict__ e_neg) {
    __shared__ float s1[4][DD], s2[4][DD];
    const int d = threadIdx.x & (DD - 1);
    const int rg = threadIdx.x >> 7;          // 0..3
    const int r0 = blockIdx.x * RPB;
    float m1 = -INFINITY, m2 = -INFINITY;
    for (int r = rg; r < RPB; r += 4) {
        int i = (r0 + r) * DD + d;
        float a = mu_min[i], b = mu_max[i];
        mu2[i] = make_float2(a, b);
        bb2[i] = make_float2(b_min[i], b_max[i]);
        m1 = fmaxf(m1, a);
        m2 = fmaxf(m2, -b);
    }
    s1[rg][d] = m1; s2[rg][d] = m2;
    __syncthreads();
    if (threadIdx.x < DD) {
        float a = fmaxf(fmaxf(s1[0][d], s1[1][d]), fmaxf(s1[2][d], s1[3][d]));
        float b = fmaxf(fmaxf(s2[0][d], s2[1][d]), fmaxf(s2[2][d], s2[3][d]));
        atomicMax(e_min + d, fenc(a));
        atomicMax(e_neg + d, fenc(b));
        if (blockIdx.x == 0) {
            mu2[P * DD + d] = make_float2(-1e38f, 1e38f);
            bb2[P * DD + d] = make_float2(0.0f, 0.0f);
        }
    }
}

// NT=512: h=tid>>8 (list half), j=(tid>>7)&1 (child), d=tid&127.
// Pass A: ballot-compacted present-parent byte-row-offsets (p<<10), padded to x16
// with sentinel. Passes B/C: register double-buffered 8-parent chunks (halves take
// alternating chunks), so 8 gathers stay in flight under the 16-exp2 consume.
template<int P, int NT>
__global__ __launch_bounds__(NT, 4)
void k_levelc(const float* __restrict__ logits, const float* __restrict__ u,
              const float2* __restrict__ bb2, const float2* __restrict__ mu2,
              const unsigned* __restrict__ e_min, const unsigned* __restrict__ e_neg,
              float* __restrict__ o_mu_min, float* __restrict__ o_mu_max,
              float* __restrict__ o_b_min, float* __restrict__ o_b_max) {
    constexpr int TC = 2;
    __shared__ __align__(16) int plist[TC * P];
    __shared__ int npres[TC];
    __shared__ int npadsh[TC];
    __shared__ float redA[2][TC][DD];
    __shared__ float redB[2][TC][DD];
    const int tid = threadIdx.x;
    const int c0 = blockIdx.x * TC;
    const int lane = tid & 63;
    if (tid < TC) npres[tid] = 0;
    __syncthreads();

    // pass A (P%64==0 so each wave's i-range stays within one j)
    for (int i = tid; i < TC * P; i += NT) {
        int j = i / P;
        int p = i - j * P;
        int idx = (c0 + j) * P + p;
        float uu = u[idx] + 1e-10f;
        float g = -__logf(-__logf(uu) + 1e-10f);
        bool pres = (logits[idx] + g) > 0.0f;
        unsigned long long m = __ballot(pres);
        int base = 0;
        if (lane == 0) base = atomicAdd(&npres[j], (int)__popcll(m));
        base = __shfl(base, 0);
        if (pres) {
            int pos = __popcll(m & ((1ull << lane) - 1));
            plist[j * P + base + pos] = p << 10;   // byte row offset
        }
    }
    __syncthreads();
    if (tid < TC) {
        int n = npres[tid];
        int npd = (n + 15) & ~15;
        if (npd == 0) npd = 16;
        for (int k = n; k < npd; ++k) plist[tid * P + k] = P << 10;  // sentinel
        npadsh[tid] = npd;
    }
    __syncthreads();

    const int h = tid >> 8;
    const int j = (tid >> 7) & (TC - 1);
    const int d = tid & (DD - 1);
    const int n = npres[j];
    const int T = npadsh[j] >> 4;             // chunks per half
    const int* pl = &plist[j * P];
    const unsigned d8 = (unsigned)(d << 3);
    const char* bbc = (const char*)bb2;
    const char* muc = (const char*)mu2;

    // ---- pass B: beta sums, double-buffered ----
    float dmn0 = 0.f, dmn1 = 0.f, dmx0 = 0.f, dmx1 = 0.f;
    {
        float2 q[8];
        int k = h * 8;
        {
            int4 A = *(const int4*)(pl + k);
            int4 B = *(const int4*)(pl + k + 4);
            q[0] = *(const float2*)(bbc + ((unsigned)A.x + d8));
            q[1] = *(const float2*)(bbc + ((unsigned)A.y + d8));
            q[2] = *(const float2*)(bbc + ((unsigned)A.z + d8));
            q[3] = *(const float2*)(bbc + ((unsigned)A.w + d8));
            q[4] = *(const float2*)(bbc + ((unsigned)B.x + d8));
            q[5] = *(const float2*)(bbc + ((unsigned)B.y + d8));
            q[6] = *(const float2*)(bbc + ((unsigned)B.z + d8));
            q[7] = *(const float2*)(bbc + ((unsigned)B.w + d8));
        }
        for (int t = 1; t < T; ++t) {
            k += 16;
            int4 A = *(const int4*)(pl + k);
            int4 B = *(const int4*)(pl + k + 4);
            float2 qn[8];
            qn[0] = *(const float2*)(bbc + ((unsigned)A.x + d8));
            qn[1] = *(const float2*)(bbc + ((unsigned)A.y + d8));
            qn[2] = *(const float2*)(bbc + ((unsigned)A.z + d8));
            qn[3] = *(const float2*)(bbc + ((unsigned)A.w + d8));
            qn[4] = *(const float2*)(bbc + ((unsigned)B.x + d8));
            qn[5] = *(const float2*)(bbc + ((unsigned)B.y + d8));
            qn[6] = *(const float2*)(bbc + ((unsigned)B.z + d8));
            qn[7] = *(const float2*)(bbc + ((unsigned)B.w + d8));
            dmn0 += (q[0].x + q[2].x) + (q[4].x + q[6].x);
            dmn1 += (q[1].x + q[3].x) + (q[5].x + q[7].x);
            dmx0 += (q[0].y + q[2].y) + (q[4].y + q[6].y);
            dmx1 += (q[1].y + q[3].y) + (q[5].y + q[7].y);
            #pragma unroll
            for (int z = 0; z < 8; ++z) q[z] = qn[z];
        }
        dmn0 += (q[0].x + q[2].x) + (q[4].x + q[6].x);
        dmn1 += (q[1].x + q[3].x) + (q[5].x + q[7].x);
        dmx0 += (q[0].y + q[2].y) + (q[4].y + q[6].y);
        dmx1 += (q[1].y + q[3].y) + (q[5].y + q[7].y);
    }
    redA[h][j][d] = dmn0 + dmn1;
    redB[h][j][d] = dmx0 + dmx1;
    __syncthreads();

    const float wsv = (float)n + 1e-10f;
    const float bmin = (redA[0][j][d] + redA[1][j][d]) / wsv;
    const float bmax = (redB[0][j][d] + redB[1][j][d]) / wsv;
    const float rmin = 1.0f / fmaxf(bmin, 1e-30f);
    const float nrmax = -1.0f / fmaxf(bmax, 1e-30f);
    const float Mmm = fdec(e_min[d]);
    const float Mng = fdec(e_neg[d]);
    const float rmin2  = rmin * LOG2E;
    const float nrmax2 = nrmax * LOG2E;
    const float negM1 = -rmin2 * Mmm;
    const float negM2 = nrmax2 * Mng;
    __syncthreads();   // before reusing redA/redB

    // ---- pass C: exp sums, double-buffered ----
    float s10 = 0.f, s11 = 0.f, s20 = 0.f, s21 = 0.f;
    {
        float2 q[8];
        int k = h * 8;
        {
            int4 A = *(const int4*)(pl + k);
            int4 B = *(const int4*)(pl + k + 4);
            q[0] = *(const float2*)(muc + ((unsigned)A.x + d8));
            q[1] = *(const float2*)(muc + ((unsigned)A.y + d8));
            q[2] = *(const float2*)(muc + ((unsigned)A.z + d8));
            q[3] = *(const float2*)(muc + ((unsigned)A.w + d8));
            q[4] = *(const float2*)(muc + ((unsigned)B.x + d8));
            q[5] = *(const float2*)(muc + ((unsigned)B.y + d8));
            q[6] = *(const float2*)(muc + ((unsigned)B.z + d8));
            q[7] = *(const float2*)(muc + ((unsigned)B.w + d8));
        }
        for (int t = 1; t < T; ++t) {
            k += 16;
            int4 A = *(const int4*)(pl + k);
            int4 B = *(const int4*)(pl + k + 4);
            float2 qn[8];
            qn[0] = *(const float2*)(muc + ((unsigned)A.x + d8));
            qn[1] = *(const float2*)(muc + ((unsigned)A.y + d8));
            qn[2] = *(const float2*)(muc + ((unsigned)A.z + d8));
            qn[3] = *(const float2*)(muc + ((unsigned)A.w + d8));
            qn[4] = *(const float2*)(muc + ((unsigned)B.x + d8));
            qn[5] = *(const float2*)(muc + ((unsigned)B.y + d8));
            qn[6] = *(const float2*)(muc + ((unsigned)B.z + d8));
            qn[7] = *(const float2*)(muc + ((unsigned)B.w + d8));
            #pragma unroll
            for (int z = 0; z < 8; z += 2) {
                s10 += __builtin_amdgcn_exp2f(fmaf(q[z].x, rmin2, negM1));
                s20 += __builtin_amdgcn_exp2f(fmaf(q[z].y, nrmax2, negM2));
                s11 += __builtin_amdgcn_exp2f(fmaf(q[z + 1].x, rmin2, negM1));
                s21 += __builtin_amdgcn_exp2f(fmaf(q[z + 1].y, nrmax2, negM2));
            }
            #pragma unroll
            for (int z = 0; z < 8; ++z) q[z] = qn[z];
        }
        #pragma unroll
        for (int z = 0; z < 8; z += 2) {
            s10 += __builtin_amdgcn_exp2f(fmaf(q[z].x, rmin2, negM1));
            s20 += __builtin_amdgcn_exp2f(fmaf(q[z].y, nrmax2, negM2));
            s11 += __builtin_amdgcn_exp2f(fmaf(q[z + 1].x, rmin2, negM1));
            s21 += __builtin_amdgcn_exp2f(fmaf(q[z + 1].y, nrmax2, negM2));
        }
    }
    redA[h][j][d] = s10 + s11;
    redB[h][j][d] = s20 + s21;
    __syncthreads();

    if (h == 0) {
        const float S1 = fmaxf(redA[0][j][d] + redA[1][j][d], 1e-35f);
        const float S2 = fmaxf(redB[0][j][d] + redB[1][j][d], 1e-35f);
        const int idx = (c0 + j) * DD + d;
        o_mu_min[idx] = bmin * fmaf(rmin, Mmm, __logf(S1));
        o_mu_max[idx] = -bmax * fmaf(-nrmax, Mng, __logf(S2));
        o_b_min[idx]  = bmin;
        o_b_max[idx]  = bmax;
    }
}

extern "C" void kernel_launch(void* const* d_in, const int* in_sizes, int n_in,
                              void* d_out, int out_size, void* d_ws, size_t ws_size,
                              hipStream_t stream) {
    const float* mu_min0  = (const float*)d_in[0];
    const float* mu_max0  = (const float*)d_in[1];
    const float* braw_min = (const float*)d_in[2];
    const float* braw_max = (const float*)d_in[3];
    const float* adj0     = (const float*)d_in[4];   // (512, 64)
    const float* adj1     = (const float*)d_in[5];   // (2048, 512)
    const float* u0       = (const float*)d_in[6];   // (1, 512, 64)
    const float* u1       = (const float*)d_in[7];   // (1, 2048, 512)
    float* out = (float*)d_out;
    float* ws = (float*)d_ws;

    unsigned* cm_enc = (unsigned*)ws;               // 512 u32: [cm0_min|cm0_neg|cm1_min|cm1_neg]
    unsigned* cm0_min = cm_enc;
    unsigned* cm0_neg = cm_enc + 128;
    unsigned* cm1_min = cm_enc + 256;
    unsigned* cm1_neg = cm_enc + 384;
    float2* mu2_0 = (float2*)(ws + 512);            // (64+1)*128 float2
    float2* bb2_0 = mu2_0 + 65 * DD;
    float2* mu2_1 = bb2_0 + 65 * DD;                // (512+1)*128 float2
    float2* bb2_1 = mu2_1 + 513 * DD;               // total ~1.19 MB

    // out offsets (f32): 0:mu_min0 8192:mu_max0 16384:bmin0 24576:bmax0
    // 32768:mu_min1 98304:mu_max1 163840:b_min1 229376:b_max1 (each 65536)
    // 294912:mu_min2 557056:mu_max2 819200:b_min2 1081344:b_max2 (each 262144)

    k_root<<<dim3(32), dim3(256), 0, stream>>>(mu_min0, mu_max0, braw_min, braw_max,
                                               out, cm_enc);

    k_packprep<64, 32><<<dim3(2), dim3(512), 0, stream>>>(
        mu_min0, mu_max0, out + 16384, out + 24576, mu2_0, bb2_0, cm0_min, cm0_neg);

    k_levelc<64, 512><<<dim3(256), dim3(512), 0, stream>>>(
        adj0, u0, bb2_0, mu2_0, cm0_min, cm0_neg,
        out + 32768, out + 98304, out + 163840, out + 229376);

    k_packprep<512, 32><<<dim3(16), dim3(512), 0, stream>>>(
        out + 32768, out + 98304, out + 163840, out + 229376, mu2_1, bb2_1, cm1_min, cm1_neg);

    k_levelc<512, 512><<<dim3(1024), dim3(512), 0, stream>>>(
        adj1, u1, bb2_1, mu2_1, cm1_min, cm1_neg,
        out + 294912, out + 557056, out + 819200, out + 1081344);
}

// Round 9
// 133.171 us; speedup vs baseline: 1.3931x; 1.2547x over previous
//
#include <hip/hip_runtime.h>
#include <cmath>

#define DD 128
#define LOG2E 1.4426950408889634f

__device__ __forceinline__ float sigm(float x) { return 1.0f / (1.0f + __expf(-x)); }

// order-preserving float<->uint encoding for atomicMax
__device__ __forceinline__ unsigned fenc(float f) {
    unsigned b = __float_as_uint(f);
    return (b & 0x80000000u) ? ~b : (b | 0x80000000u);
}
__device__ __forceinline__ float fdec(unsigned e) {
    return (e & 0x80000000u) ? __uint_as_float(e ^ 0x80000000u) : __uint_as_float(~e);
}

// Level-0 passthrough + zero the 4x128 encoded col-max slots (block 0).
__global__ void k_root(const float* __restrict__ mu_min, const float* __restrict__ mu_max,
                       const float* __restrict__ braw_min, const float* __restrict__ braw_max,
                       float* __restrict__ out, unsigned* __restrict__ cm_enc) {
    int i = blockIdx.x * 256 + threadIdx.x;   // 32 blocks x 256 = 8192
    out[i] = mu_min[i];
    out[8192 + i] = mu_max[i];
    out[16384 + i] = sigm(braw_min[i]) + 1e-6f;
    out[24576 + i] = sigm(braw_max[i]) + 1e-6f;
    if (blockIdx.x == 0) {
        cm_enc[threadIdx.x] = 0u;
        cm_enc[threadIdx.x + 256] = 0u;
    }
}

// Fused pack + column-max. mu2[p*DD+d]=(mu_min,mu_max), bb2=(b_min,b_max); sentinel
// row p=P: mu2=(-1e38,+1e38) -> exp2 underflows to exact 0; bb2=(0,0).
template<int P, int RPB>
__global__ __launch_bounds__(512)
void k_packprep(const float* __restrict__ mu_min, const float* __restrict__ mu_max,
                const float* __restrict__ b_min, const float* __restrict__ b_max,
                float2* __restrict__ mu2, float2* __restrict__ bb2,
                unsigned* __restrict__ e_min, unsigned* __restrict__ e_neg) {
    __shared__ float s1[4][DD], s2[4][DD];
    const int d = threadIdx.x & (DD - 1);
    const int rg = threadIdx.x >> 7;          // 0..3
    const int r0 = blockIdx.x * RPB;
    float m1 = -INFINITY, m2 = -INFINITY;
    for (int r = rg; r < RPB; r += 4) {
        int i = (r0 + r) * DD + d;
        float a = mu_min[i], b = mu_max[i];
        mu2[i] = make_float2(a, b);
        bb2[i] = make_float2(b_min[i], b_max[i]);
        m1 = fmaxf(m1, a);
        m2 = fmaxf(m2, -b);
    }
    s1[rg][d] = m1; s2[rg][d] = m2;
    __syncthreads();
    if (threadIdx.x < DD) {
        float a = fmaxf(fmaxf(s1[0][d], s1[1][d]), fmaxf(s1[2][d], s1[3][d]));
        float b = fmaxf(fmaxf(s2[0][d], s2[1][d]), fmaxf(s2[2][d], s2[3][d]));
        atomicMax(e_min + d, fenc(a));
        atomicMax(e_neg + d, fenc(b));
        if (blockIdx.x == 0) {
            mu2[P * DD + d] = make_float2(-1e38f, 1e38f);
            bb2[P * DD + d] = make_float2(0.0f, 0.0f);
        }
    }
}

// One WAVE per child; lane covers d-pair (2*lane, 2*lane+1). A float4 load per row
// spans the whole 1KB packed row across the wave. Wave-private list (no atomics,
// no barriers). Pass C register double-buffers 8-row chunks.
template<int P, int NWAVE>
__global__ __launch_bounds__(NWAVE * 64, 4)
void k_levelw(const float* __restrict__ logits, const float* __restrict__ u,
              const float2* __restrict__ bb2, const float2* __restrict__ mu2,
              const unsigned* __restrict__ e_min, const unsigned* __restrict__ e_neg,
              float* __restrict__ o_mu_min, float* __restrict__ o_mu_max,
              float* __restrict__ o_b_min, float* __restrict__ o_b_max) {
    __shared__ __align__(16) int plist[NWAVE * P];
    const int tid = threadIdx.x;
    const int w = tid >> 6;
    const int lane = tid & 63;
    const int c = blockIdx.x * NWAVE + w;
    int* pl = &plist[w * P];

    // pass A: wave-private present-list build (byte row offsets p<<10)
    int base = 0;
    #pragma unroll
    for (int it = 0; it < P / 64; ++it) {
        int p = it * 64 + lane;
        int idx = c * P + p;
        float uu = u[idx] + 1e-10f;
        float g = -__logf(-__logf(uu) + 1e-10f);
        bool pres = (logits[idx] + g) > 0.0f;
        unsigned long long m = __ballot(pres);
        if (pres) {
            int pos = __popcll(m & ((1ull << lane) - 1));
            pl[base + pos] = p << 10;
        }
        base += (int)__popcll(m);
    }
    const int n = base;
    int npad = (n + 7) & ~7;
    if (npad == 0) npad = 8;
    if (lane < npad - n) pl[n + lane] = P << 10;   // sentinel row

    const unsigned lb = (unsigned)(lane << 4);     // lane*16 bytes into a row
    const char* bbc = (const char*)bb2;
    const char* muc = (const char*)mu2;
    const int T = npad >> 3;

    // pass B: beta sums (q = (bmin[d0],bmax[d0],bmin[d1],bmax[d1]))
    float dmn0 = 0.f, dmx0 = 0.f, dmn1 = 0.f, dmx1 = 0.f;
    for (int k = 0; k < npad; k += 8) {
        int4 A = *(const int4*)(pl + k);
        int4 B = *(const int4*)(pl + k + 4);
        float4 r0 = *(const float4*)(bbc + ((unsigned)A.x + lb));
        float4 r1 = *(const float4*)(bbc + ((unsigned)A.y + lb));
        float4 r2 = *(const float4*)(bbc + ((unsigned)A.z + lb));
        float4 r3 = *(const float4*)(bbc + ((unsigned)A.w + lb));
        float4 r4 = *(const float4*)(bbc + ((unsigned)B.x + lb));
        float4 r5 = *(const float4*)(bbc + ((unsigned)B.y + lb));
        float4 r6 = *(const float4*)(bbc + ((unsigned)B.z + lb));
        float4 r7 = *(const float4*)(bbc + ((unsigned)B.w + lb));
        dmn0 += (r0.x + r1.x) + (r2.x + r3.x) + (r4.x + r5.x) + (r6.x + r7.x);
        dmx0 += (r0.y + r1.y) + (r2.y + r3.y) + (r4.y + r5.y) + (r6.y + r7.y);
        dmn1 += (r0.z + r1.z) + (r2.z + r3.z) + (r4.z + r5.z) + (r6.z + r7.z);
        dmx1 += (r0.w + r1.w) + (r2.w + r3.w) + (r4.w + r5.w) + (r6.w + r7.w);
    }

    const float wsv = (float)n + 1e-10f;
    const float bmin0 = dmn0 / wsv, bmax0 = dmx0 / wsv;
    const float bmin1 = dmn1 / wsv, bmax1 = dmx1 / wsv;
    const float rmin0 = 1.0f / fmaxf(bmin0, 1e-30f);
    const float rmin1 = 1.0f / fmaxf(bmin1, 1e-30f);
    const float nrmax0 = -1.0f / fmaxf(bmax0, 1e-30f);
    const float nrmax1 = -1.0f / fmaxf(bmax1, 1e-30f);
    uint2 em = *(const uint2*)(e_min + 2 * lane);
    uint2 en = *(const uint2*)(e_neg + 2 * lane);
    const float Mm0 = fdec(em.x), Mm1 = fdec(em.y);
    const float Mg0 = fdec(en.x), Mg1 = fdec(en.y);
    const float rm20 = rmin0 * LOG2E, rm21 = rmin1 * LOG2E;
    const float nx20 = nrmax0 * LOG2E, nx21 = nrmax1 * LOG2E;
    const float nM10 = -rm20 * Mm0, nM11 = -rm21 * Mm1;
    const float nM20 = nx20 * Mg0, nM21 = nx21 * Mg1;

    // pass C: double-buffered exp sums (q = (mn[d0],mx[d0],mn[d1],mx[d1]))
    float s10 = 0.f, s20 = 0.f, s11 = 0.f, s21 = 0.f;
    {
        float4 q[8];
        {
            int4 A = *(const int4*)(pl);
            int4 B = *(const int4*)(pl + 4);
            q[0] = *(const float4*)(muc + ((unsigned)A.x + lb));
            q[1] = *(const float4*)(muc + ((unsigned)A.y + lb));
            q[2] = *(const float4*)(muc + ((unsigned)A.z + lb));
            q[3] = *(const float4*)(muc + ((unsigned)A.w + lb));
            q[4] = *(const float4*)(muc + ((unsigned)B.x + lb));
            q[5] = *(const float4*)(muc + ((unsigned)B.y + lb));
            q[6] = *(const float4*)(muc + ((unsigned)B.z + lb));
            q[7] = *(const float4*)(muc + ((unsigned)B.w + lb));
        }
        int k = 0;
        for (int t = 1; t < T; ++t) {
            k += 8;
            int4 A = *(const int4*)(pl + k);
            int4 B = *(const int4*)(pl + k + 4);
            float4 qn[8];
            qn[0] = *(const float4*)(muc + ((unsigned)A.x + lb));
            qn[1] = *(const float4*)(muc + ((unsigned)A.y + lb));
            qn[2] = *(const float4*)(muc + ((unsigned)A.z + lb));
            qn[3] = *(const float4*)(muc + ((unsigned)A.w + lb));
            qn[4] = *(const float4*)(muc + ((unsigned)B.x + lb));
            qn[5] = *(const float4*)(muc + ((unsigned)B.y + lb));
            qn[6] = *(const float4*)(muc + ((unsigned)B.z + lb));
            qn[7] = *(const float4*)(muc + ((unsigned)B.w + lb));
            #pragma unroll
            for (int z = 0; z < 8; ++z) {
                s10 += __builtin_amdgcn_exp2f(fmaf(q[z].x, rm20, nM10));
                s20 += __builtin_amdgcn_exp2f(fmaf(q[z].y, nx20, nM20));
                s11 += __builtin_amdgcn_exp2f(fmaf(q[z].z, rm21, nM11));
                s21 += __builtin_amdgcn_exp2f(fmaf(q[z].w, nx21, nM21));
            }
            #pragma unroll
            for (int z = 0; z < 8; ++z) q[z] = qn[z];
        }
        #pragma unroll
        for (int z = 0; z < 8; ++z) {
            s10 += __builtin_amdgcn_exp2f(fmaf(q[z].x, rm20, nM10));
            s20 += __builtin_amdgcn_exp2f(fmaf(q[z].y, nx20, nM20));
            s11 += __builtin_amdgcn_exp2f(fmaf(q[z].z, rm21, nM11));
            s21 += __builtin_amdgcn_exp2f(fmaf(q[z].w, nx21, nM21));
        }
    }

    const int idx = c * DD + 2 * lane;
    float v10 = bmin0 * fmaf(rmin0, Mm0, __logf(fmaxf(s10, 1e-35f)));
    float v11 = bmin1 * fmaf(rmin1, Mm1, __logf(fmaxf(s11, 1e-35f)));
    float v20 = -bmax0 * fmaf(-nrmax0, Mg0, __logf(fmaxf(s20, 1e-35f)));
    float v21 = -bmax1 * fmaf(-nrmax1, Mg1, __logf(fmaxf(s21, 1e-35f)));
    *(float2*)(o_mu_min + idx) = make_float2(v10, v11);
    *(float2*)(o_mu_max + idx) = make_float2(v20, v21);
    *(float2*)(o_b_min + idx)  = make_float2(bmin0, bmin1);
    *(float2*)(o_b_max + idx)  = make_float2(bmax0, bmax1);
}

extern "C" void kernel_launch(void* const* d_in, const int* in_sizes, int n_in,
                              void* d_out, int out_size, void* d_ws, size_t ws_size,
                              hipStream_t stream) {
    const float* mu_min0  = (const float*)d_in[0];
    const float* mu_max0  = (const float*)d_in[1];
    const float* braw_min = (const float*)d_in[2];
    const float* braw_max = (const float*)d_in[3];
    const float* adj0     = (const float*)d_in[4];   // (512, 64)
    const float* adj1     = (const float*)d_in[5];   // (2048, 512)
    const float* u0       = (const float*)d_in[6];   // (1, 512, 64)
    const float* u1       = (const float*)d_in[7];   // (1, 2048, 512)
    float* out = (float*)d_out;
    float* ws = (float*)d_ws;

    unsigned* cm_enc = (unsigned*)ws;               // 512 u32
    unsigned* cm0_min = cm_enc;
    unsigned* cm0_neg = cm_enc + 128;
    unsigned* cm1_min = cm_enc + 256;
    unsigned* cm1_neg = cm_enc + 384;
    float2* mu2_0 = (float2*)(ws + 512);            // (64+1)*128 float2
    float2* bb2_0 = mu2_0 + 65 * DD;
    float2* mu2_1 = bb2_0 + 65 * DD;                // (512+1)*128 float2
    float2* bb2_1 = mu2_1 + 513 * DD;               // total ~1.19 MB

    // out offsets (f32): 0:mu_min0 8192:mu_max0 16384:bmin0 24576:bmax0
    // 32768:mu_min1 98304:mu_max1 163840:b_min1 229376:b_max1 (each 65536)
    // 294912:mu_min2 557056:mu_max2 819200:b_min2 1081344:b_max2 (each 262144)

    k_root<<<dim3(32), dim3(256), 0, stream>>>(mu_min0, mu_max0, braw_min, braw_max,
                                               out, cm_enc);

    k_packprep<64, 8><<<dim3(8), dim3(512), 0, stream>>>(
        mu_min0, mu_max0, out + 16384, out + 24576, mu2_0, bb2_0, cm0_min, cm0_neg);

    k_levelw<64, 2><<<dim3(256), dim3(128), 0, stream>>>(
        adj0, u0, bb2_0, mu2_0, cm0_min, cm0_neg,
        out + 32768, out + 98304, out + 163840, out + 229376);

    k_packprep<512, 8><<<dim3(64), dim3(512), 0, stream>>>(
        out + 32768, out + 98304, out + 163840, out + 229376, mu2_1, bb2_1, cm1_min, cm1_neg);

    k_levelw<512, 4><<<dim3(512), dim3(256), 0, stream>>>(
        adj1, u1, bb2_1, mu2_1, cm1_min, cm1_neg,
        out + 294912, out + 557056, out + 819200, out + 1081344);
}

// Round 11
// 132.065 us; speedup vs baseline: 1.4048x; 1.0084x over previous
//
#include <hip/hip_runtime.h>
#include <cmath>

#define DD 128
#define LOG2E 1.4426950408889634f

__device__ __forceinline__ float sigm(float x) { return 1.0f / (1.0f + __expf(-x)); }

// order-preserving float<->uint encoding for atomicMax
__device__ __forceinline__ unsigned fenc(float f) {
    unsigned b = __float_as_uint(f);
    return (b & 0x80000000u) ? ~b : (b | 0x80000000u);
}
__device__ __forceinline__ float fdec(unsigned e) {
    return (e & 0x80000000u) ? __uint_as_float(e ^ 0x80000000u) : __uint_as_float(~e);
}

// Fused level-0: passthrough + sigmoid betas + pack mu2_0/bb2_0 + colmax0 atomics
// + level-0 sentinel row. cm slots pre-zeroed by hipMemsetAsync.
__global__ __launch_bounds__(512)
void k_root0(const float* __restrict__ mu_min, const float* __restrict__ mu_max,
             const float* __restrict__ braw_min, const float* __restrict__ braw_max,
             float* __restrict__ out,
             float2* __restrict__ mu2_0, float2* __restrict__ bb2_0,
             unsigned* __restrict__ e_min0, unsigned* __restrict__ e_neg0) {
    __shared__ float r1[4][DD], r2[4][DD];
    const int i = blockIdx.x * 512 + threadIdx.x;       // 16 blocks x 512 = 8192
    const int rg = threadIdx.x >> 7, d = threadIdx.x & (DD - 1);
    float mn = mu_min[i], mx = mu_max[i];
    float bm = sigm(braw_min[i]) + 1e-6f;
    float bx = sigm(braw_max[i]) + 1e-6f;
    out[i] = mn; out[8192 + i] = mx; out[16384 + i] = bm; out[24576 + i] = bx;
    mu2_0[i] = make_float2(mn, mx);
    bb2_0[i] = make_float2(bm, bx);
    r1[rg][d] = mn; r2[rg][d] = -mx;
    __syncthreads();
    if (threadIdx.x < DD) {
        float a = fmaxf(fmaxf(r1[0][d], r1[1][d]), fmaxf(r1[2][d], r1[3][d]));
        float b = fmaxf(fmaxf(r2[0][d], r2[1][d]), fmaxf(r2[2][d], r2[3][d]));
        atomicMax(e_min0 + d, fenc(a));
        atomicMax(e_neg0 + d, fenc(b));
        if (blockIdx.x == 0) {
            mu2_0[64 * DD + d] = make_float2(-1e38f, 1e38f);   // sentinel row
            bb2_0[64 * DD + d] = make_float2(0.0f, 0.0f);
        }
    }
}

// Fused pack + column-max for level-1 results (verbatim from R9).
template<int P, int RPB>
__global__ __launch_bounds__(512)
void k_packprep(const float* __restrict__ mu_min, const float* __restrict__ mu_max,
                const float* __restrict__ b_min, const float* __restrict__ b_max,
                float2* __restrict__ mu2, float2* __restrict__ bb2,
                unsigned* __restrict__ e_min, unsigned* __restrict__ e_neg) {
    __shared__ float s1[4][DD], s2[4][DD];
    const int d = threadIdx.x & (DD - 1);
    const int rg = threadIdx.x >> 7;
    const int r0 = blockIdx.x * RPB;
    float m1 = -INFINITY, m2 = -INFINITY;
    for (int r = rg; r < RPB; r += 4) {
        int i = (r0 + r) * DD + d;
        float a = mu_min[i], b = mu_max[i];
        mu2[i] = make_float2(a, b);
        bb2[i] = make_float2(b_min[i], b_max[i]);
        m1 = fmaxf(m1, a);
        m2 = fmaxf(m2, -b);
    }
    s1[rg][d] = m1; s2[rg][d] = m2;
    __syncthreads();
    if (threadIdx.x < DD) {
        float a = fmaxf(fmaxf(s1[0][d], s1[1][d]), fmaxf(s1[2][d], s1[3][d]));
        float b = fmaxf(fmaxf(s2[0][d], s2[1][d]), fmaxf(s2[2][d], s2[3][d]));
        atomicMax(e_min + d, fenc(a));
        atomicMax(e_neg + d, fenc(b));
        if (blockIdx.x == 0) {
            mu2[P * DD + d] = make_float2(-1e38f, 1e38f);
            bb2[P * DD + d] = make_float2(0.0f, 0.0f);
        }
    }
}

// 256 threads = 2 children x 2 half-waves (j=w>>1, h=w&1). Lane covers d-pair
// (2*lane, 2*lane+1); one float4 load spans a whole 1KB packed row. Each wave
// builds its child's FULL list (benign duplicate writes); halves process
// alternating 8-row chunks; partials combined via LDS.
template<int P>
__global__ __launch_bounds__(256, 4)
void k_levelw(const float* __restrict__ logits, const float* __restrict__ u,
              const float2* __restrict__ bb2, const float2* __restrict__ mu2,
              const unsigned* __restrict__ e_min, const unsigned* __restrict__ e_neg,
              float* __restrict__ o_mu_min, float* __restrict__ o_mu_max,
              float* __restrict__ o_b_min, float* __restrict__ o_b_max) {
    __shared__ __align__(16) int plist[2][P];
    __shared__ float4 red[2][2][64];
    const int tid = threadIdx.x;
    const int w = tid >> 6;
    const int lane = tid & 63;
    const int j = w >> 1, h = w & 1;
    const int c = blockIdx.x * 2 + j;
    int* pl = plist[j];

    // pass A: wave-private full-list build (both halves write identical values)
    int base = 0;
    #pragma unroll
    for (int it = 0; it < P / 64; ++it) {
        int p = it * 64 + lane;
        int idx = c * P + p;
        float uu = u[idx] + 1e-10f;
        float g = -__logf(-__logf(uu) + 1e-10f);
        bool pres = (logits[idx] + g) > 0.0f;
        unsigned long long m = __ballot(pres);
        if (pres) {
            int pos = __popcll(m & ((1ull << lane) - 1));
            pl[base + pos] = p << 10;
        }
        base += (int)__popcll(m);
    }
    const int n = base;
    int npad = (n + 15) & ~15;
    if (npad == 0) npad = 16;
    if (lane < npad - n) pl[n + lane] = P << 10;   // sentinel rows

    const unsigned lb = (unsigned)(lane << 4);     // lane*16 bytes into a row
    const char* bbc = (const char*)bb2;
    const char* muc = (const char*)mu2;
    const int Th = npad >> 4;                      // 8-row chunks per half-wave

    // pass B: beta sums (r = (bmin[d0],bmax[d0],bmin[d1],bmax[d1]))
    float dmn0 = 0.f, dmx0 = 0.f, dmn1 = 0.f, dmx1 = 0.f;
    {
        float4 q[8];
        int k = h * 8;
        {
            int4 A = *(const int4*)(pl + k);
            int4 B = *(const int4*)(pl + k + 4);
            q[0] = *(const float4*)(bbc + ((unsigned)A.x + lb));
            q[1] = *(const float4*)(bbc + ((unsigned)A.y + lb));
            q[2] = *(const float4*)(bbc + ((unsigned)A.z + lb));
            q[3] = *(const float4*)(bbc + ((unsigned)A.w + lb));
            q[4] = *(const float4*)(bbc + ((unsigned)B.x + lb));
            q[5] = *(const float4*)(bbc + ((unsigned)B.y + lb));
            q[6] = *(const float4*)(bbc + ((unsigned)B.z + lb));
            q[7] = *(const float4*)(bbc + ((unsigned)B.w + lb));
        }
        for (int t = 1; t < Th; ++t) {
            k += 16;
            int4 A = *(const int4*)(pl + k);
            int4 B = *(const int4*)(pl + k + 4);
            float4 qn[8];
            qn[0] = *(const float4*)(bbc + ((unsigned)A.x + lb));
            qn[1] = *(const float4*)(bbc + ((unsigned)A.y + lb));
            qn[2] = *(const float4*)(bbc + ((unsigned)A.z + lb));
            qn[3] = *(const float4*)(bbc + ((unsigned)A.w + lb));
            qn[4] = *(const float4*)(bbc + ((unsigned)B.x + lb));
            qn[5] = *(const float4*)(bbc + ((unsigned)B.y + lb));
            qn[6] = *(const float4*)(bbc + ((unsigned)B.z + lb));
            qn[7] = *(const float4*)(bbc + ((unsigned)B.w + lb));
            dmn0 += (q[0].x + q[1].x) + (q[2].x + q[3].x) + (q[4].x + q[5].x) + (q[6].x + q[7].x);
            dmx0 += (q[0].y + q[1].y) + (q[2].y + q[3].y) + (q[4].y + q[5].y) + (q[6].y + q[7].y);
            dmn1 += (q[0].z + q[1].z) + (q[2].z + q[3].z) + (q[4].z + q[5].z) + (q[6].z + q[7].z);
            dmx1 += (q[0].w + q[1].w) + (q[2].w + q[3].w) + (q[4].w + q[5].w) + (q[6].w + q[7].w);
            #pragma unroll
            for (int z = 0; z < 8; ++z) q[z] = qn[z];
        }
        dmn0 += (q[0].x + q[1].x) + (q[2].x + q[3].x) + (q[4].x + q[5].x) + (q[6].x + q[7].x);
        dmx0 += (q[0].y + q[1].y) + (q[2].y + q[3].y) + (q[4].y + q[5].y) + (q[6].y + q[7].y);
        dmn1 += (q[0].z + q[1].z) + (q[2].z + q[3].z) + (q[4].z + q[5].z) + (q[6].z + q[7].z);
        dmx1 += (q[0].w + q[1].w) + (q[2].w + q[3].w) + (q[4].w + q[5].w) + (q[6].w + q[7].w);
    }
    red[j][h][lane] = make_float4(dmn0, dmx0, dmn1, dmx1);
    __syncthreads();

    float4 pb0 = red[j][0][lane];
    float4 pb1 = red[j][1][lane];
    const float wsv = (float)n + 1e-10f;
    const float bmin0 = (pb0.x + pb1.x) / wsv;
    const float bmax0 = (pb0.y + pb1.y) / wsv;
    const float bmin1 = (pb0.z + pb1.z) / wsv;
    const float bmax1 = (pb0.w + pb1.w) / wsv;
    const float rmin0 = 1.0f / fmaxf(bmin0, 1e-30f);
    const float rmin1 = 1.0f / fmaxf(bmin1, 1e-30f);
    const float nrmax0 = -1.0f / fmaxf(bmax0, 1e-30f);
    const float nrmax1 = -1.0f / fmaxf(bmax1, 1e-30f);
    uint2 em = *(const uint2*)(e_min + 2 * lane);
    uint2 en = *(const uint2*)(e_neg + 2 * lane);
    const float Mm0 = fdec(em.x), Mm1 = fdec(em.y);
    const float Mg0 = fdec(en.x), Mg1 = fdec(en.y);
    const float rm20 = rmin0 * LOG2E, rm21 = rmin1 * LOG2E;
    const float nx20 = nrmax0 * LOG2E, nx21 = nrmax1 * LOG2E;
    const float nM10 = -rm20 * Mm0, nM11 = -rm21 * Mm1;
    const float nM20 = nx20 * Mg0, nM21 = nx21 * Mg1;
    __syncthreads();   // red free for reuse

    // pass C: exp sums (q = (mn[d0],mx[d0],mn[d1],mx[d1]))
    float s10 = 0.f, s20 = 0.f, s11 = 0.f, s21 = 0.f;
    {
        float4 q[8];
        int k = h * 8;
        {
            int4 A = *(const int4*)(pl + k);
            int4 B = *(const int4*)(pl + k + 4);
            q[0] = *(const float4*)(muc + ((unsigned)A.x + lb));
            q[1] = *(const float4*)(muc + ((unsigned)A.y + lb));
            q[2] = *(const float4*)(muc + ((unsigned)A.z + lb));
            q[3] = *(const float4*)(muc + ((unsigned)A.w + lb));
            q[4] = *(const float4*)(muc + ((unsigned)B.x + lb));
            q[5] = *(const float4*)(muc + ((unsigned)B.y + lb));
            q[6] = *(const float4*)(muc + ((unsigned)B.z + lb));
            q[7] = *(const float4*)(muc + ((unsigned)B.w + lb));
        }
        for (int t = 1; t < Th; ++t) {
            k += 16;
            int4 A = *(const int4*)(pl + k);
            int4 B = *(const int4*)(pl + k + 4);
            float4 qn[8];
            qn[0] = *(const float4*)(muc + ((unsigned)A.x + lb));
            qn[1] = *(const float4*)(muc + ((unsigned)A.y + lb));
            qn[2] = *(const float4*)(muc + ((unsigned)A.z + lb));
            qn[3] = *(const float4*)(muc + ((unsigned)A.w + lb));
            qn[4] = *(const float4*)(muc + ((unsigned)B.x + lb));
            qn[5] = *(const float4*)(muc + ((unsigned)B.y + lb));
            qn[6] = *(const float4*)(muc + ((unsigned)B.z + lb));
            qn[7] = *(const float4*)(muc + ((unsigned)B.w + lb));
            #pragma unroll
            for (int z = 0; z < 8; ++z) {
                s10 += __builtin_amdgcn_exp2f(fmaf(q[z].x, rm20, nM10));
                s20 += __builtin_amdgcn_exp2f(fmaf(q[z].y, nx20, nM20));
                s11 += __builtin_amdgcn_exp2f(fmaf(q[z].z, rm21, nM11));
                s21 += __builtin_amdgcn_exp2f(fmaf(q[z].w, nx21, nM21));
            }
            #pragma unroll
            for (int z = 0; z < 8; ++z) q[z] = qn[z];
        }
        #pragma unroll
        for (int z = 0; z < 8; ++z) {
            s10 += __builtin_amdgcn_exp2f(fmaf(q[z].x, rm20, nM10));
            s20 += __builtin_amdgcn_exp2f(fmaf(q[z].y, nx20, nM20));
            s11 += __builtin_amdgcn_exp2f(fmaf(q[z].z, rm21, nM11));
            s21 += __builtin_amdgcn_exp2f(fmaf(q[z].w, nx21, nM21));
        }
    }
    red[j][h][lane] = make_float4(s10, s20, s11, s21);
    __syncthreads();

    if (h == 0) {
        float4 pc0 = red[j][0][lane];
        float4 pc1 = red[j][1][lane];
        const float S10 = fmaxf(pc0.x + pc1.x, 1e-35f);
        const float S20 = fmaxf(pc0.y + pc1.y, 1e-35f);
        const float S11 = fmaxf(pc0.z + pc1.z, 1e-35f);
        const float S21 = fmaxf(pc0.w + pc1.w, 1e-35f);
        const int idx = c * DD + 2 * lane;
        float v10 = bmin0 * fmaf(rmin0, Mm0, __logf(S10));
        float v11 = bmin1 * fmaf(rmin1, Mm1, __logf(S11));
        float v20 = -bmax0 * fmaf(-nrmax0, Mg0, __logf(S20));
        float v21 = -bmax1 * fmaf(-nrmax1, Mg1, __logf(S21));
        *(float2*)(o_mu_min + idx) = make_float2(v10, v11);
        *(float2*)(o_mu_max + idx) = make_float2(v20, v21);
        *(float2*)(o_b_min + idx)  = make_float2(bmin0, bmin1);
        *(float2*)(o_b_max + idx)  = make_float2(bmax0, bmax1);
    }
}

extern "C" void kernel_launch(void* const* d_in, const int* in_sizes, int n_in,
                              void* d_out, int out_size, void* d_ws, size_t ws_size,
                              hipStream_t stream) {
    const float* mu_min0  = (const float*)d_in[0];
    const float* mu_max0  = (const float*)d_in[1];
    const float* braw_min = (const float*)d_in[2];
    const float* braw_max = (const float*)d_in[3];
    const float* adj0     = (const float*)d_in[4];   // (512, 64)
    const float* adj1     = (const float*)d_in[5];   // (2048, 512)
    const float* u0       = (const float*)d_in[6];   // (1, 512, 64)
    const float* u1       = (const float*)d_in[7];   // (1, 2048, 512)
    float* out = (float*)d_out;
    float* ws = (float*)d_ws;

    unsigned* cm_enc  = (unsigned*)ws;              // 512 u32
    unsigned* cm0_min = cm_enc;
    unsigned* cm0_neg = cm_enc + 128;
    unsigned* cm1_min = cm_enc + 256;
    unsigned* cm1_neg = cm_enc + 384;
    float2* mu2_0 = (float2*)(ws + 512);            // (64+1)*128 float2
    float2* bb2_0 = mu2_0 + 65 * DD;
    float2* mu2_1 = bb2_0 + 65 * DD;                // (512+1)*128 float2
    float2* bb2_1 = mu2_1 + 513 * DD;               // total ~1.19 MB

    // out offsets (f32): 0:mu_min0 8192:mu_max0 16384:bmin0 24576:bmax0
    // 32768:mu_min1 98304:mu_max1 163840:b_min1 229376:b_max1 (each 65536)
    // 294912:mu_min2 557056:mu_max2 819200:b_min2 1081344:b_max2 (each 262144)

    hipMemsetAsync(cm_enc, 0, 512 * sizeof(unsigned), stream);

    k_root0<<<dim3(16), dim3(512), 0, stream>>>(
        mu_min0, mu_max0, braw_min, braw_max, out, mu2_0, bb2_0, cm0_min, cm0_neg);

    k_levelw<64><<<dim3(256), dim3(256), 0, stream>>>(
        adj0, u0, bb2_0, mu2_0, cm0_min, cm0_neg,
        out + 32768, out + 98304, out + 163840, out + 229376);

    k_packprep<512, 8><<<dim3(64), dim3(512), 0, stream>>>(
        out + 32768, out + 98304, out + 163840, out + 229376, mu2_1, bb2_1, cm1_min, cm1_neg);

    k_levelw<512><<<dim3(1024), dim3(256), 0, stream>>>(
        adj1, u1, bb2_1, mu2_1, cm1_min, cm1_neg,
        out + 294912, out + 557056, out + 819200, out + 1081344);
}

// Round 12
// 125.423 us; speedup vs baseline: 1.4791x; 1.0530x over previous
//
#include <hip/hip_runtime.h>
#include <cmath>

#define DD 128
#define LOG2E 1.4426950408889634f

__device__ __forceinline__ float sigm(float x) { return 1.0f / (1.0f + __expf(-x)); }

// order-preserving float<->uint encoding for atomicMax
__device__ __forceinline__ unsigned fenc(float f) {
    unsigned b = __float_as_uint(f);
    return (b & 0x80000000u) ? ~b : (b | 0x80000000u);
}
__device__ __forceinline__ float fdec(unsigned e) {
    return (e & 0x80000000u) ? __uint_as_float(e ^ 0x80000000u) : __uint_as_float(~e);
}

// Fused level-0: passthrough + sigmoid betas + pack mu2_0/bb2_0 + colmax0 atomics
// + level-0 sentinel row. cm slots pre-zeroed by hipMemsetAsync.
__global__ __launch_bounds__(512)
void k_root0(const float* __restrict__ mu_min, const float* __restrict__ mu_max,
             const float* __restrict__ braw_min, const float* __restrict__ braw_max,
             float* __restrict__ out,
             float2* __restrict__ mu2_0, float2* __restrict__ bb2_0,
             unsigned* __restrict__ e_min0, unsigned* __restrict__ e_neg0) {
    __shared__ float r1[4][DD], r2[4][DD];
    const int i = blockIdx.x * 512 + threadIdx.x;       // 16 blocks x 512 = 8192
    const int rg = threadIdx.x >> 7, d = threadIdx.x & (DD - 1);
    float mn = mu_min[i], mx = mu_max[i];
    float bm = sigm(braw_min[i]) + 1e-6f;
    float bx = sigm(braw_max[i]) + 1e-6f;
    out[i] = mn; out[8192 + i] = mx; out[16384 + i] = bm; out[24576 + i] = bx;
    mu2_0[i] = make_float2(mn, mx);
    bb2_0[i] = make_float2(bm, bx);
    r1[rg][d] = mn; r2[rg][d] = -mx;
    __syncthreads();
    if (threadIdx.x < DD) {
        float a = fmaxf(fmaxf(r1[0][d], r1[1][d]), fmaxf(r1[2][d], r1[3][d]));
        float b = fmaxf(fmaxf(r2[0][d], r2[1][d]), fmaxf(r2[2][d], r2[3][d]));
        atomicMax(e_min0 + d, fenc(a));
        atomicMax(e_neg0 + d, fenc(b));
        if (blockIdx.x == 0) {
            mu2_0[64 * DD + d] = make_float2(-1e38f, 1e38f);   // sentinel row
            bb2_0[64 * DD + d] = make_float2(0.0f, 0.0f);
        }
    }
}

// Fused pack + column-max for level-1 results.
template<int P, int RPB>
__global__ __launch_bounds__(512)
void k_packprep(const float* __restrict__ mu_min, const float* __restrict__ mu_max,
                const float* __restrict__ b_min, const float* __restrict__ b_max,
                float2* __restrict__ mu2, float2* __restrict__ bb2,
                unsigned* __restrict__ e_min, unsigned* __restrict__ e_neg) {
    __shared__ float s1[4][DD], s2[4][DD];
    const int d = threadIdx.x & (DD - 1);
    const int rg = threadIdx.x >> 7;
    const int r0 = blockIdx.x * RPB;
    float m1 = -INFINITY, m2 = -INFINITY;
    for (int r = rg; r < RPB; r += 4) {
        int i = (r0 + r) * DD + d;
        float a = mu_min[i], b = mu_max[i];
        mu2[i] = make_float2(a, b);
        bb2[i] = make_float2(b_min[i], b_max[i]);
        m1 = fmaxf(m1, a);
        m2 = fmaxf(m2, -b);
    }
    s1[rg][d] = m1; s2[rg][d] = m2;
    __syncthreads();
    if (threadIdx.x < DD) {
        float a = fmaxf(fmaxf(s1[0][d], s1[1][d]), fmaxf(s1[2][d], s1[3][d]));
        float b = fmaxf(fmaxf(s2[0][d], s2[1][d]), fmaxf(s2[2][d], s2[3][d]));
        atomicMax(e_min + d, fenc(a));
        atomicMax(e_neg + d, fenc(b));
        if (blockIdx.x == 0) {
            mu2[P * DD + d] = make_float2(-1e38f, 1e38f);
            bb2[P * DD + d] = make_float2(0.0f, 0.0f);
        }
    }
}

// Level-1 (sparse, R11-verbatim): 2 children x 2 half-waves per 256-thread block.
template<int P>
__global__ __launch_bounds__(256, 4)
void k_levelw(const float* __restrict__ logits, const float* __restrict__ u,
              const float2* __restrict__ bb2, const float2* __restrict__ mu2,
              const unsigned* __restrict__ e_min, const unsigned* __restrict__ e_neg,
              float* __restrict__ o_mu_min, float* __restrict__ o_mu_max,
              float* __restrict__ o_b_min, float* __restrict__ o_b_max) {
    __shared__ __align__(16) int plist[2][P];
    __shared__ float4 red[2][2][64];
    const int tid = threadIdx.x;
    const int w = tid >> 6;
    const int lane = tid & 63;
    const int j = w >> 1, h = w & 1;
    const int c = blockIdx.x * 2 + j;
    int* pl = plist[j];

    int base = 0;
    #pragma unroll
    for (int it = 0; it < P / 64; ++it) {
        int p = it * 64 + lane;
        int idx = c * P + p;
        float uu = u[idx] + 1e-10f;
        float g = -__logf(-__logf(uu) + 1e-10f);
        bool pres = (logits[idx] + g) > 0.0f;
        unsigned long long m = __ballot(pres);
        if (pres) {
            int pos = __popcll(m & ((1ull << lane) - 1));
            pl[base + pos] = p << 10;
        }
        base += (int)__popcll(m);
    }
    const int n = base;
    int npad = (n + 15) & ~15;
    if (npad == 0) npad = 16;
    if (lane < npad - n) pl[n + lane] = P << 10;

    const unsigned lb = (unsigned)(lane << 4);
    const char* bbc = (const char*)bb2;
    const char* muc = (const char*)mu2;
    const int Th = npad >> 4;

    float dmn0 = 0.f, dmx0 = 0.f, dmn1 = 0.f, dmx1 = 0.f;
    for (int t = 0; t < Th; ++t) {
        int k = h * 8 + t * 16;
        int4 A = *(const int4*)(pl + k);
        int4 B = *(const int4*)(pl + k + 4);
        float4 q0 = *(const float4*)(bbc + ((unsigned)A.x + lb));
        float4 q1 = *(const float4*)(bbc + ((unsigned)A.y + lb));
        float4 q2 = *(const float4*)(bbc + ((unsigned)A.z + lb));
        float4 q3 = *(const float4*)(bbc + ((unsigned)A.w + lb));
        float4 q4 = *(const float4*)(bbc + ((unsigned)B.x + lb));
        float4 q5 = *(const float4*)(bbc + ((unsigned)B.y + lb));
        float4 q6 = *(const float4*)(bbc + ((unsigned)B.z + lb));
        float4 q7 = *(const float4*)(bbc + ((unsigned)B.w + lb));
        dmn0 += (q0.x + q1.x) + (q2.x + q3.x) + (q4.x + q5.x) + (q6.x + q7.x);
        dmx0 += (q0.y + q1.y) + (q2.y + q3.y) + (q4.y + q5.y) + (q6.y + q7.y);
        dmn1 += (q0.z + q1.z) + (q2.z + q3.z) + (q4.z + q5.z) + (q6.z + q7.z);
        dmx1 += (q0.w + q1.w) + (q2.w + q3.w) + (q4.w + q5.w) + (q6.w + q7.w);
    }
    red[j][h][lane] = make_float4(dmn0, dmx0, dmn1, dmx1);
    __syncthreads();

    float4 pb0 = red[j][0][lane];
    float4 pb1 = red[j][1][lane];
    const float wsv = (float)n + 1e-10f;
    const float bmin0 = (pb0.x + pb1.x) / wsv;
    const float bmax0 = (pb0.y + pb1.y) / wsv;
    const float bmin1 = (pb0.z + pb1.z) / wsv;
    const float bmax1 = (pb0.w + pb1.w) / wsv;
    const float rmin0 = 1.0f / fmaxf(bmin0, 1e-30f);
    const float rmin1 = 1.0f / fmaxf(bmin1, 1e-30f);
    const float nrmax0 = -1.0f / fmaxf(bmax0, 1e-30f);
    const float nrmax1 = -1.0f / fmaxf(bmax1, 1e-30f);
    uint2 em = *(const uint2*)(e_min + 2 * lane);
    uint2 en = *(const uint2*)(e_neg + 2 * lane);
    const float Mm0 = fdec(em.x), Mm1 = fdec(em.y);
    const float Mg0 = fdec(en.x), Mg1 = fdec(en.y);
    const float rm20 = rmin0 * LOG2E, rm21 = rmin1 * LOG2E;
    const float nx20 = nrmax0 * LOG2E, nx21 = nrmax1 * LOG2E;
    const float nM10 = -rm20 * Mm0, nM11 = -rm21 * Mm1;
    const float nM20 = nx20 * Mg0, nM21 = nx21 * Mg1;
    __syncthreads();

    float s10 = 0.f, s20 = 0.f, s11 = 0.f, s21 = 0.f;
    for (int t = 0; t < Th; ++t) {
        int k = h * 8 + t * 16;
        int4 A = *(const int4*)(pl + k);
        int4 B = *(const int4*)(pl + k + 4);
        float4 q0 = *(const float4*)(muc + ((unsigned)A.x + lb));
        float4 q1 = *(const float4*)(muc + ((unsigned)A.y + lb));
        float4 q2 = *(const float4*)(muc + ((unsigned)A.z + lb));
        float4 q3 = *(const float4*)(muc + ((unsigned)A.w + lb));
        float4 q4 = *(const float4*)(muc + ((unsigned)B.x + lb));
        float4 q5 = *(const float4*)(muc + ((unsigned)B.y + lb));
        float4 q6 = *(const float4*)(muc + ((unsigned)B.z + lb));
        float4 q7 = *(const float4*)(muc + ((unsigned)B.w + lb));
        s10 += __builtin_amdgcn_exp2f(fmaf(q0.x, rm20, nM10));
        s20 += __builtin_amdgcn_exp2f(fmaf(q0.y, nx20, nM20));
        s11 += __builtin_amdgcn_exp2f(fmaf(q0.z, rm21, nM11));
        s21 += __builtin_amdgcn_exp2f(fmaf(q0.w, nx21, nM21));
        s10 += __builtin_amdgcn_exp2f(fmaf(q1.x, rm20, nM10));
        s20 += __builtin_amdgcn_exp2f(fmaf(q1.y, nx20, nM20));
        s11 += __builtin_amdgcn_exp2f(fmaf(q1.z, rm21, nM11));
        s21 += __builtin_amdgcn_exp2f(fmaf(q1.w, nx21, nM21));
        s10 += __builtin_amdgcn_exp2f(fmaf(q2.x, rm20, nM10));
        s20 += __builtin_amdgcn_exp2f(fmaf(q2.y, nx20, nM20));
        s11 += __builtin_amdgcn_exp2f(fmaf(q2.z, rm21, nM11));
        s21 += __builtin_amdgcn_exp2f(fmaf(q2.w, nx21, nM21));
        s10 += __builtin_amdgcn_exp2f(fmaf(q3.x, rm20, nM10));
        s20 += __builtin_amdgcn_exp2f(fmaf(q3.y, nx20, nM20));
        s11 += __builtin_amdgcn_exp2f(fmaf(q3.z, rm21, nM11));
        s21 += __builtin_amdgcn_exp2f(fmaf(q3.w, nx21, nM21));
        s10 += __builtin_amdgcn_exp2f(fmaf(q4.x, rm20, nM10));
        s20 += __builtin_amdgcn_exp2f(fmaf(q4.y, nx20, nM20));
        s11 += __builtin_amdgcn_exp2f(fmaf(q4.z, rm21, nM11));
        s21 += __builtin_amdgcn_exp2f(fmaf(q4.w, nx21, nM21));
        s10 += __builtin_amdgcn_exp2f(fmaf(q5.x, rm20, nM10));
        s20 += __builtin_amdgcn_exp2f(fmaf(q5.y, nx20, nM20));
        s11 += __builtin_amdgcn_exp2f(fmaf(q5.z, rm21, nM11));
        s21 += __builtin_amdgcn_exp2f(fmaf(q5.w, nx21, nM21));
        s10 += __builtin_amdgcn_exp2f(fmaf(q6.x, rm20, nM10));
        s20 += __builtin_amdgcn_exp2f(fmaf(q6.y, nx20, nM20));
        s11 += __builtin_amdgcn_exp2f(fmaf(q6.z, rm21, nM11));
        s21 += __builtin_amdgcn_exp2f(fmaf(q6.w, nx21, nM21));
        s10 += __builtin_amdgcn_exp2f(fmaf(q7.x, rm20, nM10));
        s20 += __builtin_amdgcn_exp2f(fmaf(q7.y, nx20, nM20));
        s11 += __builtin_amdgcn_exp2f(fmaf(q7.z, rm21, nM11));
        s21 += __builtin_amdgcn_exp2f(fmaf(q7.w, nx21, nM21));
    }
    red[j][h][lane] = make_float4(s10, s20, s11, s21);
    __syncthreads();

    if (h == 0) {
        float4 pc0 = red[j][0][lane];
        float4 pc1 = red[j][1][lane];
        const float S10 = fmaxf(pc0.x + pc1.x, 1e-35f);
        const float S20 = fmaxf(pc0.y + pc1.y, 1e-35f);
        const float S11 = fmaxf(pc0.z + pc1.z, 1e-35f);
        const float S21 = fmaxf(pc0.w + pc1.w, 1e-35f);
        const int idx = c * DD + 2 * lane;
        float v10 = bmin0 * fmaf(rmin0, Mm0, __logf(S10));
        float v11 = bmin1 * fmaf(rmin1, Mm1, __logf(S11));
        float v20 = -bmax0 * fmaf(-nrmax0, Mg0, __logf(S20));
        float v21 = -bmax1 * fmaf(-nrmax1, Mg1, __logf(S21));
        *(float2*)(o_mu_min + idx) = make_float2(v10, v11);
        *(float2*)(o_mu_max + idx) = make_float2(v20, v21);
        *(float2*)(o_b_min + idx)  = make_float2(bmin0, bmin1);
        *(float2*)(o_b_max + idx)  = make_float2(bmax0, bmax1);
    }
}

// Level-2 DENSE: 512 threads = 8 waves; 4 children share one dense row stream.
// Wave w streams rows [w*64, w*64+64); each row applied to all 4 children via
// wf in LDS (w=1 or 1e-10 — exactly the reference's log(w+eps) term). Partial
// sums LDS-reduced across waves; per-child constants computed by 256 reducers.
__global__ __launch_bounds__(512, 4)
void k_level2d(const float* __restrict__ logits, const float* __restrict__ u,
               const float2* __restrict__ bb2, const float2* __restrict__ mu2,
               const unsigned* __restrict__ e_min, const unsigned* __restrict__ e_neg,
               float* __restrict__ o_mu_min, float* __restrict__ o_mu_max,
               float* __restrict__ o_b_min, float* __restrict__ o_b_max) {
    constexpr int P = 512, TC = 4;
    __shared__ __align__(16) float wsh[P][TC];     // wf per (row, child)
    __shared__ int npres[TC];
    __shared__ float4 red[8][TC][64];              // per-wave partials
    __shared__ float4 carrA[TC][64], carrB[TC][64];// broadcast constants
    const int tid = threadIdx.x;
    const int w = tid >> 6;
    const int lane = tid & 63;
    const int c0 = blockIdx.x * TC;
    if (tid < TC) npres[tid] = 0;
    __syncthreads();

    // pass A: wf = pres ? 1 : 1e-10 for all (child, row); popcount per child.
    #pragma unroll
    for (int it = 0; it < TC; ++it) {
        int i = it * 512 + tid;
        int j = i >> 9;
        int p = i & 511;
        int idx = (c0 + j) * P + p;
        float uu = u[idx] + 1e-10f;
        float g = -__logf(-__logf(uu) + 1e-10f);
        bool pres = (logits[idx] + g) > 0.0f;
        wsh[p][j] = pres ? 1.0f : 1e-10f;
        unsigned long long m = __ballot(pres);
        if (lane == 0) atomicAdd(&npres[j], (int)__popcll(m));
    }
    __syncthreads();

    const unsigned lb = (unsigned)(lane << 4);
    const char* bbc = (const char*)bb2 + (unsigned)(w * 64) * 1024u + lb;
    const char* muc = (const char*)mu2 + (unsigned)(w * 64) * 1024u + lb;
    const int p0 = w * 64;

    // pass B: beta sums, dense over this wave's 64 rows, all 4 children.
    float4 accB[TC];
    #pragma unroll
    for (int j = 0; j < TC; ++j) accB[j] = make_float4(0.f, 0.f, 0.f, 0.f);
    for (int z = 0; z < 64; z += 4) {
        float4 q0 = *(const float4*)(bbc + (unsigned)(z + 0) * 1024u);
        float4 q1 = *(const float4*)(bbc + (unsigned)(z + 1) * 1024u);
        float4 q2 = *(const float4*)(bbc + (unsigned)(z + 2) * 1024u);
        float4 q3 = *(const float4*)(bbc + (unsigned)(z + 3) * 1024u);
        float4 w0 = *(const float4*)wsh[p0 + z + 0];
        float4 w1 = *(const float4*)wsh[p0 + z + 1];
        float4 w2 = *(const float4*)wsh[p0 + z + 2];
        float4 w3 = *(const float4*)wsh[p0 + z + 3];
        const float* wf0 = (const float*)&w0;
        const float* wf1 = (const float*)&w1;
        const float* wf2 = (const float*)&w2;
        const float* wf3 = (const float*)&w3;
        #pragma unroll
        for (int j = 0; j < TC; ++j) {
            accB[j].x = fmaf(wf0[j], q0.x, fmaf(wf1[j], q1.x, fmaf(wf2[j], q2.x, fmaf(wf3[j], q3.x, accB[j].x))));
            accB[j].y = fmaf(wf0[j], q0.y, fmaf(wf1[j], q1.y, fmaf(wf2[j], q2.y, fmaf(wf3[j], q3.y, accB[j].y))));
            accB[j].z = fmaf(wf0[j], q0.z, fmaf(wf1[j], q1.z, fmaf(wf2[j], q2.z, fmaf(wf3[j], q3.z, accB[j].z))));
            accB[j].w = fmaf(wf0[j], q0.w, fmaf(wf1[j], q1.w, fmaf(wf2[j], q2.w, fmaf(wf3[j], q3.w, accB[j].w))));
        }
    }
    #pragma unroll
    for (int j = 0; j < TC; ++j) red[w][j][lane] = accB[j];
    __syncthreads();

    // reducers: one thread per (child, lane) computes constants + keeps finals.
    float bmin0, bmax0, bmin1, bmax1, rmin0, rmin1, nrmax0, nrmax1, Mm0, Mm1, Mg0, Mg1;
    const int rj = tid >> 6;       // child for reducer threads (tid < 256)
    if (tid < 256) {
        float4 S = red[0][rj][lane];
        #pragma unroll
        for (int ww = 1; ww < 8; ++ww) {
            float4 t = red[ww][rj][lane];
            S.x += t.x; S.y += t.y; S.z += t.z; S.w += t.w;
        }
        const float wsv = (float)npres[rj] + 1e-10f;
        bmin0 = S.x / wsv; bmax0 = S.y / wsv; bmin1 = S.z / wsv; bmax1 = S.w / wsv;
        rmin0 = 1.0f / fmaxf(bmin0, 1e-30f);
        rmin1 = 1.0f / fmaxf(bmin1, 1e-30f);
        nrmax0 = -1.0f / fmaxf(bmax0, 1e-30f);
        nrmax1 = -1.0f / fmaxf(bmax1, 1e-30f);
        uint2 em = *(const uint2*)(e_min + 2 * lane);
        uint2 en = *(const uint2*)(e_neg + 2 * lane);
        Mm0 = fdec(em.x); Mm1 = fdec(em.y);
        Mg0 = fdec(en.x); Mg1 = fdec(en.y);
        float rm20 = rmin0 * LOG2E, rm21 = rmin1 * LOG2E;
        float nx20 = nrmax0 * LOG2E, nx21 = nrmax1 * LOG2E;
        carrA[rj][lane] = make_float4(rm20, rm21, nx20, nx21);
        carrB[rj][lane] = make_float4(-rm20 * Mm0, -rm21 * Mm1, nx20 * Mg0, nx21 * Mg1);
    }
    __syncthreads();

    // all threads: fetch per-(child, lane) constants.
    float4 cA[TC], cB[TC];
    #pragma unroll
    for (int j = 0; j < TC; ++j) { cA[j] = carrA[j][lane]; cB[j] = carrB[j][lane]; }

    // pass C: exp sums, dense.
    float4 accS[TC];
    #pragma unroll
    for (int j = 0; j < TC; ++j) accS[j] = make_float4(0.f, 0.f, 0.f, 0.f);
    for (int z = 0; z < 64; z += 2) {
        float4 q0 = *(const float4*)(muc + (unsigned)(z + 0) * 1024u);
        float4 q1 = *(const float4*)(muc + (unsigned)(z + 1) * 1024u);
        float4 w0 = *(const float4*)wsh[p0 + z + 0];
        float4 w1 = *(const float4*)wsh[p0 + z + 1];
        const float* wf0 = (const float*)&w0;
        const float* wf1 = (const float*)&w1;
        #pragma unroll
        for (int j = 0; j < TC; ++j) {
            accS[j].x = fmaf(wf0[j], __builtin_amdgcn_exp2f(fmaf(q0.x, cA[j].x, cB[j].x)), accS[j].x);
            accS[j].y = fmaf(wf0[j], __builtin_amdgcn_exp2f(fmaf(q0.y, cA[j].z, cB[j].z)), accS[j].y);
            accS[j].z = fmaf(wf0[j], __builtin_amdgcn_exp2f(fmaf(q0.z, cA[j].y, cB[j].y)), accS[j].z);
            accS[j].w = fmaf(wf0[j], __builtin_amdgcn_exp2f(fmaf(q0.w, cA[j].w, cB[j].w)), accS[j].w);
            accS[j].x = fmaf(wf1[j], __builtin_amdgcn_exp2f(fmaf(q1.x, cA[j].x, cB[j].x)), accS[j].x);
            accS[j].y = fmaf(wf1[j], __builtin_amdgcn_exp2f(fmaf(q1.y, cA[j].z, cB[j].z)), accS[j].y);
            accS[j].z = fmaf(wf1[j], __builtin_amdgcn_exp2f(fmaf(q1.z, cA[j].y, cB[j].y)), accS[j].z);
            accS[j].w = fmaf(wf1[j], __builtin_amdgcn_exp2f(fmaf(q1.w, cA[j].w, cB[j].w)), accS[j].w);
        }
    }
    #pragma unroll
    for (int j = 0; j < TC; ++j) red[w][j][lane] = accS[j];
    __syncthreads();

    if (tid < 256) {
        float4 S = red[0][rj][lane];
        #pragma unroll
        for (int ww = 1; ww < 8; ++ww) {
            float4 t = red[ww][rj][lane];
            S.x += t.x; S.y += t.y; S.z += t.z; S.w += t.w;
        }
        const float S10 = fmaxf(S.x, 1e-35f);
        const float S20 = fmaxf(S.y, 1e-35f);
        const float S11 = fmaxf(S.z, 1e-35f);
        const float S21 = fmaxf(S.w, 1e-35f);
        const int idx = (c0 + rj) * DD + 2 * lane;
        float v10 = bmin0 * fmaf(rmin0, Mm0, __logf(S10));
        float v11 = bmin1 * fmaf(rmin1, Mm1, __logf(S11));
        float v20 = -bmax0 * fmaf(-nrmax0, Mg0, __logf(S20));
        float v21 = -bmax1 * fmaf(-nrmax1, Mg1, __logf(S21));
        *(float2*)(o_mu_min + idx) = make_float2(v10, v11);
        *(float2*)(o_mu_max + idx) = make_float2(v20, v21);
        *(float2*)(o_b_min + idx)  = make_float2(bmin0, bmin1);
        *(float2*)(o_b_max + idx)  = make_float2(bmax0, bmax1);
    }
}

extern "C" void kernel_launch(void* const* d_in, const int* in_sizes, int n_in,
                              void* d_out, int out_size, void* d_ws, size_t ws_size,
                              hipStream_t stream) {
    const float* mu_min0  = (const float*)d_in[0];
    const float* mu_max0  = (const float*)d_in[1];
    const float* braw_min = (const float*)d_in[2];
    const float* braw_max = (const float*)d_in[3];
    const float* adj0     = (const float*)d_in[4];   // (512, 64)
    const float* adj1     = (const float*)d_in[5];   // (2048, 512)
    const float* u0       = (const float*)d_in[6];   // (1, 512, 64)
    const float* u1       = (const float*)d_in[7];   // (1, 2048, 512)
    float* out = (float*)d_out;
    float* ws = (float*)d_ws;

    unsigned* cm_enc  = (unsigned*)ws;              // 512 u32
    unsigned* cm0_min = cm_enc;
    unsigned* cm0_neg = cm_enc + 128;
    unsigned* cm1_min = cm_enc + 256;
    unsigned* cm1_neg = cm_enc + 384;
    float2* mu2_0 = (float2*)(ws + 512);            // (64+1)*128 float2
    float2* bb2_0 = mu2_0 + 65 * DD;
    float2* mu2_1 = bb2_0 + 65 * DD;                // (512+1)*128 float2
    float2* bb2_1 = mu2_1 + 513 * DD;               // total ~1.19 MB

    // out offsets (f32): 0:mu_min0 8192:mu_max0 16384:bmin0 24576:bmax0
    // 32768:mu_min1 98304:mu_max1 163840:b_min1 229376:b_max1 (each 65536)
    // 294912:mu_min2 557056:mu_max2 819200:b_min2 1081344:b_max2 (each 262144)

    hipMemsetAsync(cm_enc, 0, 512 * sizeof(unsigned), stream);

    k_root0<<<dim3(16), dim3(512), 0, stream>>>(
        mu_min0, mu_max0, braw_min, braw_max, out, mu2_0, bb2_0, cm0_min, cm0_neg);

    k_levelw<64><<<dim3(256), dim3(256), 0, stream>>>(
        adj0, u0, bb2_0, mu2_0, cm0_min, cm0_neg,
        out + 32768, out + 98304, out + 163840, out + 229376);

    k_packprep<512, 8><<<dim3(64), dim3(512), 0, stream>>>(
        out + 32768, out + 98304, out + 163840, out + 229376, mu2_1, bb2_1, cm1_min, cm1_neg);

    k_level2d<<<dim3(512), dim3(512), 0, stream>>>(
        adj1, u1, bb2_1, mu2_1, cm1_min, cm1_neg,
        out + 294912, out + 557056, out + 819200, out + 1081344);
}